// Round 1
// baseline (6621.490 us; speedup 1.0000x reference)
//
#include <hip/hip_runtime.h>

#define N_  128
#define C_  64
#define T_  128
#define V_  25
#define CO_ 128
#define H_  3
#define D_  16
#define KT_ 7

constexpr float EPSF = 1e-5f;

// ---- workspace layout (in floats) ----
constexpr size_t QK_SZ   = (size_t)N_ * 96 * T_ * V_;        // 39,321,600
constexpr size_t ATT_SZ  = (size_t)N_ * H_ * V_ * V_;        // 240,000
constexpr size_t X2_SZ   = (size_t)N_ * CO_ * T_ * V_;       // 52,428,800
constexpr size_t OFF_QK  = 0;
constexpr size_t OFF_ATT = OFF_QK + QK_SZ;
constexpr size_t OFF_X2  = OFF_ATT + ATT_SZ;
constexpr size_t OFF_W   = OFF_X2 + X2_SZ;
constexpr size_t OFF_WQKVT = OFF_W;                          // 64*96
constexpr size_t OFF_WOUTT = OFF_WQKVT + 64 * 96;            // 192*128
constexpr size_t OFF_BOUT  = OFF_WOUTT + 192 * 128;          // 128
constexpr size_t OFF_WRESST= OFF_BOUT + 128;                 // 64*128
constexpr size_t OFF_BRESS = OFF_WRESST + 64 * 128;          // 128
constexpr size_t OFF_WFFT  = OFF_BRESS + 128;                // 128*128
constexpr size_t OFF_BFF   = OFF_WFFT + 128 * 128;           // 128
constexpr size_t OFF_WTT   = OFF_BFF + 128;                  // 128*7*128
constexpr size_t OFF_BT    = OFF_WTT + 128 * 7 * 128;        // 128
constexpr size_t OFF_WRESTT= OFF_BT + 128;                   // 128*128
constexpr size_t OFF_BREST = OFF_WRESTT + 128 * 128;         // 128

__device__ __forceinline__ float lrelu(float y) { return y >= 0.f ? y : 0.1f * y; }

// ---- K0: fold BN into weights, transpose weight matrices ----
__global__ void k0_prep(const float* __restrict__ w_qkv,
                        const float* __restrict__ w_out, const float* __restrict__ b_out,
                        const float* __restrict__ g_out, const float* __restrict__ be_out,
                        const float* __restrict__ m_out, const float* __restrict__ v_out,
                        const float* __restrict__ w_ff,  const float* __restrict__ b_ff,
                        const float* __restrict__ g_ff,  const float* __restrict__ be_ff,
                        const float* __restrict__ m_ff,  const float* __restrict__ v_ff,
                        const float* __restrict__ w_t,   const float* __restrict__ b_t,
                        const float* __restrict__ g_t,   const float* __restrict__ be_t,
                        const float* __restrict__ m_t,   const float* __restrict__ v_t,
                        const float* __restrict__ w_ress,const float* __restrict__ b_ress,
                        const float* __restrict__ g_ress,const float* __restrict__ be_ress,
                        const float* __restrict__ m_ress,const float* __restrict__ v_ress,
                        const float* __restrict__ w_rest,const float* __restrict__ b_rest,
                        const float* __restrict__ g_rest,const float* __restrict__ be_rest,
                        const float* __restrict__ m_rest,const float* __restrict__ v_rest,
                        float* __restrict__ ws)
{
    int tid = blockIdx.x * blockDim.x + threadIdx.x;
    int np = gridDim.x * blockDim.x;

    for (int i = tid; i < 64 * 96; i += np) {
        int c = i / 96, o = i % 96;
        ws[OFF_WQKVT + i] = w_qkv[o * 64 + c];
    }
    for (int i = tid; i < 192 * 128; i += np) {
        int hc = i / 128, o = i % 128;
        float sc = g_out[o] * rsqrtf(v_out[o] + EPSF);
        ws[OFF_WOUTT + i] = w_out[o * 192 + hc] * sc;
    }
    for (int i = tid; i < 64 * 128; i += np) {
        int c = i / 128, o = i % 128;
        float sc = g_ress[o] * rsqrtf(v_ress[o] + EPSF);
        ws[OFF_WRESST + i] = w_ress[o * 64 + c] * sc;
    }
    for (int i = tid; i < 128 * 128; i += np) {
        int c = i / 128, o = i % 128;
        float sc = g_ff[o] * rsqrtf(v_ff[o] + EPSF);
        ws[OFF_WFFT + i] = w_ff[o * 128 + c] * sc;
    }
    for (int i = tid; i < 128 * 128; i += np) {
        int c = i / 128, o = i % 128;
        float sc = g_rest[o] * rsqrtf(v_rest[o] + EPSF);
        ws[OFF_WRESTT + i] = w_rest[o * 128 + c] * sc;
    }
    for (int idx = tid; idx < 128 * 7 * 128; idx += np) {
        int o = idx % 128, ik = idx / 128;
        int i = ik / 7, k = ik % 7;
        float sc = g_t[o] * rsqrtf(v_t[o] + EPSF);
        ws[OFF_WTT + idx] = w_t[((size_t)o * 128 + i) * 7 + k] * sc;
    }
    for (int o = tid; o < 128; o += np) {
        float sco = g_out[o] * rsqrtf(v_out[o] + EPSF);
        ws[OFF_BOUT + o] = (b_out[o] - m_out[o]) * sco + be_out[o];
        float scr = g_ress[o] * rsqrtf(v_ress[o] + EPSF);
        ws[OFF_BRESS + o] = (b_ress[o] - m_ress[o]) * scr + be_ress[o];
        float scf = g_ff[o] * rsqrtf(v_ff[o] + EPSF);
        ws[OFF_BFF + o] = (b_ff[o] - m_ff[o]) * scf + be_ff[o];
        float sct = g_t[o] * rsqrtf(v_t[o] + EPSF);
        ws[OFF_BT + o] = (b_t[o] - m_t[o]) * sct + be_t[o];
        float sce = g_rest[o] * rsqrtf(v_rest[o] + EPSF);
        ws[OFF_BREST + o] = (b_rest[o] - m_rest[o]) * sce + be_rest[o];
    }
}

// ---- K1: qkv conv1x1 -> qk[n,96,t,v] ----
__global__ __launch_bounds__(256) void k1_qkv(const float* __restrict__ x,
                                              const float* __restrict__ b_qkv,
                                              const float* __restrict__ ws,
                                              float* __restrict__ qk)
{
    __shared__ float Xs[64][26];
    __shared__ float Wq[64][96];
    int nt = blockIdx.x;
    int n = nt / T_, t = nt % T_;
    const float* xb = x + ((size_t)n * C_ * T_ + t) * V_;
    for (int e = threadIdx.x; e < 64 * 25; e += 256) {
        int c = e / 25, v = e % 25;
        Xs[c][v] = xb[(size_t)c * T_ * V_ + v];
    }
    const float* wq = ws + OFF_WQKVT;
    for (int e = threadIdx.x; e < 64 * 96; e += 256) {
        Wq[e / 96][e % 96] = wq[e];
    }
    __syncthreads();
    float* qb = qk + ((size_t)n * 96 * T_ + t) * V_;
    for (int e = threadIdx.x; e < 96 * 25; e += 256) {
        int o = e / 25, v = e % 25;
        float acc = b_qkv[o];
#pragma unroll
        for (int c = 0; c < 64; ++c) acc += Wq[c][o] * Xs[c][v];
        qb[(size_t)o * T_ * V_ + v] = acc;
    }
}

// ---- K2: attention logits + softmax -> att[n,h,u,v] ----
__global__ __launch_bounds__(256) void k2_att(const float* __restrict__ qk,
                                              const float* __restrict__ values,
                                              const float* __restrict__ att_bias,
                                              float* __restrict__ att)
{
    int nh = blockIdx.x;
    int n = nh / H_, h = nh % H_;
    __shared__ float Qs[D_][8][26];
    __shared__ float Ks[D_][8][26];
    __shared__ float L[V_][V_ + 1];
    float acc[3] = {0.f, 0.f, 0.f};
    const float* qbase = qk + ((size_t)(n * 96 + h * 16) * T_) * V_;
    const float* kbase = qk + ((size_t)(n * 96 + 48 + h * 16) * T_) * V_;
    for (int tc = 0; tc < T_; tc += 8) {
        __syncthreads();
        for (int e = threadIdx.x; e < 16 * 8 * 25; e += 256) {
            int d = e / 200, r = e % 200;
            int tt = r / 25, u = r % 25;
            Qs[d][tt][u] = qbase[((size_t)d * T_ + tc + tt) * V_ + u];
            Ks[d][tt][u] = kbase[((size_t)d * T_ + tc + tt) * V_ + u];
        }
        __syncthreads();
#pragma unroll
        for (int p = 0; p < 3; ++p) {
            int e = threadIdx.x + p * 256;
            if (e < 625) {
                int u = e / 25, v = e % 25;
                float a = acc[p];
                for (int tt = 0; tt < 8; ++tt) {
#pragma unroll
                    for (int d = 0; d < 16; ++d)
                        a += Qs[d][tt][u] * Ks[d][tt][v];
                }
                acc[p] = a;
            }
        }
    }
    float scale = values[h] / 2048.0f;
    float bias = att_bias[h];
#pragma unroll
    for (int p = 0; p < 3; ++p) {
        int e = threadIdx.x + p * 256;
        if (e < 625) L[e / 25][e % 25] = acc[p] * scale + bias;
    }
    __syncthreads();
    if (threadIdx.x < 25) {
        int u = threadIdx.x;
        float m = -1e30f;
        for (int v = 0; v < 25; ++v) m = fmaxf(m, L[u][v]);
        float ex[25];
        float s = 0.f;
        for (int v = 0; v < 25; ++v) { ex[v] = expf(L[u][v] - m); s += ex[v]; }
        float inv = 1.0f / s;
        float* ab = att + ((size_t)(n * 3 + h) * 25 + u) * 25;
        for (int v = 0; v < 25; ++v) ab[v] = ex[v] * inv;
    }
}

// ---- K3: xs = x*att, x1 = lrelu(bn(conv_out(xs)) + bn(conv_ress(x))) ----
__global__ __launch_bounds__(256) void k3_x1(const float* __restrict__ x,
                                             const float* __restrict__ att,
                                             const float* __restrict__ ws,
                                             float* __restrict__ x1)
{
    __shared__ float Xs[64][26];
    __shared__ float As[3][25][26];
    __shared__ float Tm[192][26];
    int nt = blockIdx.x;
    int n = nt / T_, t = nt % T_;
    const float* xb = x + ((size_t)n * C_ * T_ + t) * V_;
    for (int e = threadIdx.x; e < 64 * 25; e += 256) {
        int c = e / 25, v = e % 25;
        Xs[c][v] = xb[(size_t)c * T_ * V_ + v];
    }
    const float* ab = att + (size_t)n * 3 * 625;
    for (int e = threadIdx.x; e < 3 * 625; e += 256) {
        int h = e / 625, r = e % 625;
        As[h][r / 25][r % 25] = ab[e];
    }
    __syncthreads();
    for (int e = threadIdx.x; e < 192 * 25; e += 256) {
        int hc = e / 25, v = e % 25;
        int h = hc >> 6, c = hc & 63;
        float a = 0.f;
#pragma unroll
        for (int u = 0; u < 25; ++u) a += Xs[c][u] * As[h][u][v];
        Tm[hc][v] = a;
    }
    __syncthreads();
    const float* woutT = ws + OFF_WOUTT;
    const float* bout  = ws + OFF_BOUT;
    const float* wressT= ws + OFF_WRESST;
    const float* bress = ws + OFF_BRESS;
    float* ob = x1 + ((size_t)n * CO_ * T_ + t) * V_;
    for (int e = threadIdx.x; e < 128 * 25; e += 256) {
        int o = e / 25, v = e % 25;
        float a = bout[o];
#pragma unroll 8
        for (int hc = 0; hc < 192; ++hc) a += woutT[hc * 128 + o] * Tm[hc][v];
        float r = bress[o];
#pragma unroll 8
        for (int c = 0; c < 64; ++c) r += wressT[c * 128 + o] * Xs[c][v];
        ob[(size_t)o * T_ * V_ + v] = lrelu(a + r);
    }
}

// ---- K4: x2 = lrelu(bn(conv_ff(x1)) + bn(conv_ress(x))) ----
__global__ __launch_bounds__(256) void k4_x2(const float* __restrict__ x,
                                             const float* __restrict__ x1,
                                             const float* __restrict__ ws,
                                             float* __restrict__ x2)
{
    __shared__ float X1s[128][26];
    __shared__ float Xs[64][26];
    int nt = blockIdx.x;
    int n = nt / T_, t = nt % T_;
    const float* xb = x + ((size_t)n * C_ * T_ + t) * V_;
    const float* x1b = x1 + ((size_t)n * CO_ * T_ + t) * V_;
    for (int e = threadIdx.x; e < 64 * 25; e += 256) {
        int c = e / 25, v = e % 25;
        Xs[c][v] = xb[(size_t)c * T_ * V_ + v];
    }
    for (int e = threadIdx.x; e < 128 * 25; e += 256) {
        int c = e / 25, v = e % 25;
        X1s[c][v] = x1b[(size_t)c * T_ * V_ + v];
    }
    __syncthreads();
    const float* wffT  = ws + OFF_WFFT;
    const float* bff   = ws + OFF_BFF;
    const float* wressT= ws + OFF_WRESST;
    const float* bress = ws + OFF_BRESS;
    float* ob = x2 + ((size_t)n * CO_ * T_ + t) * V_;
    for (int e = threadIdx.x; e < 128 * 25; e += 256) {
        int o = e / 25, v = e % 25;
        float a = bff[o];
#pragma unroll 8
        for (int c = 0; c < 128; ++c) a += wffT[c * 128 + o] * X1s[c][v];
        float r = bress[o];
#pragma unroll 8
        for (int c = 0; c < 64; ++c) r += wressT[c * 128 + o] * Xs[c][v];
        ob[(size_t)o * T_ * V_ + v] = lrelu(a + r);
    }
}

// ---- K5: temporal conv (K=7) + conv_rest + final lrelu ----
__global__ __launch_bounds__(256) void k5_out(const float* __restrict__ x2,
                                              const float* __restrict__ ws,
                                              float* __restrict__ out)
{
    __shared__ float X2c[64][7][26];
    int nt = blockIdx.x;
    int n = nt / T_, t = nt % T_;
    const float* x2b = x2 + (size_t)n * CO_ * T_ * V_;
    const float* wtT = ws + OFF_WTT;
    const float* wrestT = ws + OFF_WRESTT;
    int og = threadIdx.x & 127;
    int vh = threadIdx.x >> 7;
    int v0 = vh * 13;
    int nv = vh ? 12 : 13;
    float acc[13], racc[13];
#pragma unroll
    for (int j = 0; j < 13; ++j) { acc[j] = 0.f; racc[j] = 0.f; }
    for (int ic = 0; ic < 2; ++ic) {
        __syncthreads();
        for (int e = threadIdx.x; e < 64 * 7 * 26; e += 256) {
            int ii = e / 182, r = e % 182;
            int k = r / 26, v = r % 26;
            int tp = t + k - 3;
            float val = 0.f;
            if (v < 25 && tp >= 0 && tp < T_)
                val = x2b[((size_t)(ic * 64 + ii) * T_ + tp) * V_ + v];
            X2c[ii][k][v] = val;
        }
        __syncthreads();
        for (int ii = 0; ii < 64; ++ii) {
            int i = ic * 64 + ii;
#pragma unroll
            for (int k = 0; k < 7; ++k) {
                float w = wtT[((size_t)i * 7 + k) * 128 + og];
#pragma unroll
                for (int j = 0; j < 13; ++j) acc[j] += w * X2c[ii][k][v0 + j];
            }
            float wr = wrestT[i * 128 + og];
#pragma unroll
            for (int j = 0; j < 13; ++j) racc[j] += wr * X2c[ii][3][v0 + j];
        }
    }
    const float* bt = ws + OFF_BT;
    const float* brest = ws + OFF_BREST;
    float bsum_t = bt[og], bsum_r = brest[og];
    float* ob = out + ((size_t)n * CO_ * T_ + t) * V_ + (size_t)og * T_ * V_;
    for (int j = 0; j < nv; ++j) {
        float y = acc[j] + bsum_t + racc[j] + bsum_r;
        ob[v0 + j] = lrelu(y);
    }
}

extern "C" void kernel_launch(void* const* d_in, const int* in_sizes, int n_in,
                              void* d_out, int out_size, void* d_ws, size_t ws_size,
                              hipStream_t stream)
{
    const float* x       = (const float*)d_in[0];
    const float* w_qkv   = (const float*)d_in[1];
    const float* b_qkv   = (const float*)d_in[2];
    const float* values  = (const float*)d_in[3];
    const float* att_bias= (const float*)d_in[4];
    const float* w_out   = (const float*)d_in[5];
    const float* b_out   = (const float*)d_in[6];
    const float* g_out   = (const float*)d_in[7];
    const float* be_out  = (const float*)d_in[8];
    const float* m_out   = (const float*)d_in[9];
    const float* v_out   = (const float*)d_in[10];
    const float* w_ff    = (const float*)d_in[11];
    const float* b_ff    = (const float*)d_in[12];
    const float* g_ff    = (const float*)d_in[13];
    const float* be_ff   = (const float*)d_in[14];
    const float* m_ff    = (const float*)d_in[15];
    const float* v_ff    = (const float*)d_in[16];
    const float* w_t     = (const float*)d_in[17];
    const float* b_t     = (const float*)d_in[18];
    const float* g_t     = (const float*)d_in[19];
    const float* be_t    = (const float*)d_in[20];
    const float* m_t     = (const float*)d_in[21];
    const float* v_t     = (const float*)d_in[22];
    const float* w_ress  = (const float*)d_in[23];
    const float* b_ress  = (const float*)d_in[24];
    const float* g_ress  = (const float*)d_in[25];
    const float* be_ress = (const float*)d_in[26];
    const float* m_ress  = (const float*)d_in[27];
    const float* v_ress  = (const float*)d_in[28];
    const float* w_rest  = (const float*)d_in[29];
    const float* b_rest  = (const float*)d_in[30];
    const float* g_rest  = (const float*)d_in[31];
    const float* be_rest = (const float*)d_in[32];
    const float* m_rest  = (const float*)d_in[33];
    const float* v_rest  = (const float*)d_in[34];

    float* ws = (float*)d_ws;
    float* out = (float*)d_out;

    k0_prep<<<128, 256, 0, stream>>>(w_qkv,
        w_out, b_out, g_out, be_out, m_out, v_out,
        w_ff, b_ff, g_ff, be_ff, m_ff, v_ff,
        w_t, b_t, g_t, be_t, m_t, v_t,
        w_ress, b_ress, g_ress, be_ress, m_ress, v_ress,
        w_rest, b_rest, g_rest, be_rest, m_rest, v_rest,
        ws);
    k1_qkv<<<N_ * T_, 256, 0, stream>>>(x, b_qkv, ws, ws + OFF_QK);
    k2_att<<<N_ * H_, 256, 0, stream>>>(ws + OFF_QK, values, att_bias, ws + OFF_ATT);
    k3_x1<<<N_ * T_, 256, 0, stream>>>(x, ws + OFF_ATT, ws, out);
    k4_x2<<<N_ * T_, 256, 0, stream>>>(x, out, ws, ws + OFF_X2);
    k5_out<<<N_ * T_, 256, 0, stream>>>(ws + OFF_X2, ws, out);
}

// Round 2
// 4012.632 us; speedup vs baseline: 1.6502x; 1.6502x over previous
//
#include <hip/hip_runtime.h>

#define N_  128
#define C_  64
#define T_  128
#define V_  25
#define CO_ 128
#define H_  3
#define D_  16
#define KT_ 7

constexpr float EPSF = 1e-5f;

typedef __attribute__((ext_vector_type(8))) short short8;
typedef __attribute__((ext_vector_type(8))) unsigned short ushort8;
typedef __attribute__((ext_vector_type(4))) float f32x4;

// ---- workspace layout (in float units) ----
constexpr size_t QK_SZ     = (size_t)N_ * 96 * T_ * V_;         // 39,321,600
constexpr size_t ATT_SZ    = (size_t)N_ * H_ * V_ * V_;         // 240,000
constexpr size_t X2T_HALF  = (size_t)N_ * 3200 * 128 / 2;       // ushorts/2 = 26,214,400 floats
constexpr size_t OFF_QK    = 0;
constexpr size_t OFF_ATT   = OFF_QK + QK_SZ;
constexpr size_t OFF_X2HI  = OFF_ATT + ATT_SZ;
constexpr size_t OFF_X2LO  = OFF_X2HI + X2T_HALF;
constexpr size_t OFF_W     = OFF_X2LO + X2T_HALF;
constexpr size_t OFF_WQKVT = OFF_W;                             // 64*96
constexpr size_t OFF_WOUTT = OFF_WQKVT + 64 * 96;               // 192*128
constexpr size_t OFF_BOUT  = OFF_WOUTT + 192 * 128;             // 128
constexpr size_t OFF_WRESST= OFF_BOUT + 128;                    // 64*128
constexpr size_t OFF_BRESS = OFF_WRESST + 64 * 128;             // 128
constexpr size_t OFF_WFFT  = OFF_BRESS + 128;                   // 128*128
constexpr size_t OFF_BFF   = OFF_WFFT + 128 * 128;              // 128
constexpr size_t OFF_BCOMB = OFF_BFF + 128;                     // 128
constexpr size_t OFF_WAHI  = OFF_BCOMB + 128;                   // 128*1024 ushorts = 65536 floats
constexpr size_t OFF_WALO  = OFF_WAHI + 65536;                  // 65536 floats

__device__ __forceinline__ float lrelu(float y) { return y >= 0.f ? y : 0.1f * y; }

__device__ __forceinline__ unsigned short f2bf_rne(float f) {
    unsigned int u = __builtin_bit_cast(unsigned int, f);
    u += 0x7FFFu + ((u >> 16) & 1u);
    return (unsigned short)(u >> 16);
}
__device__ __forceinline__ float bf2f(unsigned short b) {
    unsigned int u = ((unsigned int)b) << 16;
    return __builtin_bit_cast(float, u);
}

// ---- K0: fold BN into weights, transpose; build bf16 hi/lo A-planes for k5 ----
__global__ void k0_prep(const float* __restrict__ w_qkv,
                        const float* __restrict__ w_out, const float* __restrict__ b_out,
                        const float* __restrict__ g_out, const float* __restrict__ be_out,
                        const float* __restrict__ m_out, const float* __restrict__ v_out,
                        const float* __restrict__ w_ff,  const float* __restrict__ b_ff,
                        const float* __restrict__ g_ff,  const float* __restrict__ be_ff,
                        const float* __restrict__ m_ff,  const float* __restrict__ v_ff,
                        const float* __restrict__ w_t,   const float* __restrict__ b_t,
                        const float* __restrict__ g_t,   const float* __restrict__ be_t,
                        const float* __restrict__ m_t,   const float* __restrict__ v_t,
                        const float* __restrict__ w_ress,const float* __restrict__ b_ress,
                        const float* __restrict__ g_ress,const float* __restrict__ be_ress,
                        const float* __restrict__ m_ress,const float* __restrict__ v_ress,
                        const float* __restrict__ w_rest,const float* __restrict__ b_rest,
                        const float* __restrict__ g_rest,const float* __restrict__ be_rest,
                        const float* __restrict__ m_rest,const float* __restrict__ v_rest,
                        float* __restrict__ ws)
{
    int tid = blockIdx.x * blockDim.x + threadIdx.x;
    int np = gridDim.x * blockDim.x;

    for (int i = tid; i < 64 * 96; i += np) {
        int c = i / 96, o = i % 96;
        ws[OFF_WQKVT + i] = w_qkv[o * 64 + c];
    }
    for (int i = tid; i < 192 * 128; i += np) {
        int hc = i / 128, o = i % 128;
        float sc = g_out[o] * rsqrtf(v_out[o] + EPSF);
        ws[OFF_WOUTT + i] = w_out[o * 192 + hc] * sc;
    }
    for (int i = tid; i < 64 * 128; i += np) {
        int c = i / 128, o = i % 128;
        float sc = g_ress[o] * rsqrtf(v_ress[o] + EPSF);
        ws[OFF_WRESST + i] = w_ress[o * 64 + c] * sc;
    }
    for (int i = tid; i < 128 * 128; i += np) {
        int c = i / 128, o = i % 128;
        float sc = g_ff[o] * rsqrtf(v_ff[o] + EPSF);
        ws[OFF_WFFT + i] = w_ff[o * 128 + c] * sc;
    }
    // A-planes for the fused temporal+rest GEMM: A[o][kk], kk = tap*128 + i (tap 7 = rest)
    {
        unsigned short* wAhi = (unsigned short*)(ws + OFF_WAHI);
        unsigned short* wAlo = (unsigned short*)(ws + OFF_WALO);
        for (int idx = tid; idx < 128 * 1024; idx += np) {
            int o = idx >> 10, kk = idx & 1023;
            int tap = kk >> 7, i = kk & 127;
            float val;
            if (tap < 7) {
                float sc = g_t[o] * rsqrtf(v_t[o] + EPSF);
                val = w_t[((size_t)o * 128 + i) * 7 + tap] * sc;
            } else {
                float sc = g_rest[o] * rsqrtf(v_rest[o] + EPSF);
                val = w_rest[o * 128 + i] * sc;
            }
            unsigned short hi = f2bf_rne(val);
            float lo = val - bf2f(hi);
            wAhi[idx] = hi;
            wAlo[idx] = f2bf_rne(lo);
        }
    }
    for (int o = tid; o < 128; o += np) {
        float sco = g_out[o] * rsqrtf(v_out[o] + EPSF);
        ws[OFF_BOUT + o] = (b_out[o] - m_out[o]) * sco + be_out[o];
        float scr = g_ress[o] * rsqrtf(v_ress[o] + EPSF);
        ws[OFF_BRESS + o] = (b_ress[o] - m_ress[o]) * scr + be_ress[o];
        float scf = g_ff[o] * rsqrtf(v_ff[o] + EPSF);
        ws[OFF_BFF + o] = (b_ff[o] - m_ff[o]) * scf + be_ff[o];
        float sct = g_t[o] * rsqrtf(v_t[o] + EPSF);
        float sce = g_rest[o] * rsqrtf(v_rest[o] + EPSF);
        ws[OFF_BCOMB + o] = (b_t[o] - m_t[o]) * sct + be_t[o]
                          + (b_rest[o] - m_rest[o]) * sce + be_rest[o];
    }
}

// ---- K1: qkv conv1x1 -> qk[n,96,t,v] ----
__global__ __launch_bounds__(256) void k1_qkv(const float* __restrict__ x,
                                              const float* __restrict__ b_qkv,
                                              const float* __restrict__ ws,
                                              float* __restrict__ qk)
{
    __shared__ float Xs[64][26];
    __shared__ float Wq[64][96];
    int nt = blockIdx.x;
    int n = nt / T_, t = nt % T_;
    const float* xb = x + ((size_t)n * C_ * T_ + t) * V_;
    for (int e = threadIdx.x; e < 64 * 25; e += 256) {
        int c = e / 25, v = e % 25;
        Xs[c][v] = xb[(size_t)c * T_ * V_ + v];
    }
    const float* wq = ws + OFF_WQKVT;
    for (int e = threadIdx.x; e < 64 * 96; e += 256) {
        Wq[e / 96][e % 96] = wq[e];
    }
    __syncthreads();
    float* qb = qk + ((size_t)n * 96 * T_ + t) * V_;
    for (int e = threadIdx.x; e < 96 * 25; e += 256) {
        int o = e / 25, v = e % 25;
        float acc = b_qkv[o];
#pragma unroll
        for (int c = 0; c < 64; ++c) acc += Wq[c][o] * Xs[c][v];
        qb[(size_t)o * T_ * V_ + v] = acc;
    }
}

// ---- K2: attention logits + softmax -> att[n,h,u,v] ----
__global__ __launch_bounds__(256) void k2_att(const float* __restrict__ qk,
                                              const float* __restrict__ values,
                                              const float* __restrict__ att_bias,
                                              float* __restrict__ att)
{
    int nh = blockIdx.x;
    int n = nh / H_, h = nh % H_;
    __shared__ float Qs[D_][8][26];
    __shared__ float Ks[D_][8][26];
    __shared__ float L[V_][V_ + 1];
    float acc[3] = {0.f, 0.f, 0.f};
    const float* qbase = qk + ((size_t)(n * 96 + h * 16) * T_) * V_;
    const float* kbase = qk + ((size_t)(n * 96 + 48 + h * 16) * T_) * V_;
    for (int tc = 0; tc < T_; tc += 8) {
        __syncthreads();
        for (int e = threadIdx.x; e < 16 * 8 * 25; e += 256) {
            int d = e / 200, r = e % 200;
            int tt = r / 25, u = r % 25;
            Qs[d][tt][u] = qbase[((size_t)d * T_ + tc + tt) * V_ + u];
            Ks[d][tt][u] = kbase[((size_t)d * T_ + tc + tt) * V_ + u];
        }
        __syncthreads();
#pragma unroll
        for (int p = 0; p < 3; ++p) {
            int e = threadIdx.x + p * 256;
            if (e < 625) {
                int u = e / 25, v = e % 25;
                float a = acc[p];
                for (int tt = 0; tt < 8; ++tt) {
#pragma unroll
                    for (int d = 0; d < 16; ++d)
                        a += Qs[d][tt][u] * Ks[d][tt][v];
                }
                acc[p] = a;
            }
        }
    }
    float scale = values[h] / 2048.0f;
    float bias = att_bias[h];
#pragma unroll
    for (int p = 0; p < 3; ++p) {
        int e = threadIdx.x + p * 256;
        if (e < 625) L[e / 25][e % 25] = acc[p] * scale + bias;
    }
    __syncthreads();
    if (threadIdx.x < 25) {
        int u = threadIdx.x;
        float m = -1e30f;
        for (int v = 0; v < 25; ++v) m = fmaxf(m, L[u][v]);
        float ex[25];
        float s = 0.f;
        for (int v = 0; v < 25; ++v) { ex[v] = expf(L[u][v] - m); s += ex[v]; }
        float inv = 1.0f / s;
        float* ab = att + ((size_t)(n * 3 + h) * 25 + u) * 25;
        for (int v = 0; v < 25; ++v) ab[v] = ex[v] * inv;
    }
}

// ---- K3: xs = x*att, x1 = lrelu(bn(conv_out(xs)) + bn(conv_ress(x))) ----
__global__ __launch_bounds__(256) void k3_x1(const float* __restrict__ x,
                                             const float* __restrict__ att,
                                             const float* __restrict__ ws,
                                             float* __restrict__ x1)
{
    __shared__ float Xs[64][26];
    __shared__ float As[3][25][26];
    __shared__ float Tm[192][26];
    int nt = blockIdx.x;
    int n = nt / T_, t = nt % T_;
    const float* xb = x + ((size_t)n * C_ * T_ + t) * V_;
    for (int e = threadIdx.x; e < 64 * 25; e += 256) {
        int c = e / 25, v = e % 25;
        Xs[c][v] = xb[(size_t)c * T_ * V_ + v];
    }
    const float* ab = att + (size_t)n * 3 * 625;
    for (int e = threadIdx.x; e < 3 * 625; e += 256) {
        int h = e / 625, r = e % 625;
        As[h][r / 25][r % 25] = ab[e];
    }
    __syncthreads();
    for (int e = threadIdx.x; e < 192 * 25; e += 256) {
        int hc = e / 25, v = e % 25;
        int h = hc >> 6, c = hc & 63;
        float a = 0.f;
#pragma unroll
        for (int u = 0; u < 25; ++u) a += Xs[c][u] * As[h][u][v];
        Tm[hc][v] = a;
    }
    __syncthreads();
    const float* woutT = ws + OFF_WOUTT;
    const float* bout  = ws + OFF_BOUT;
    const float* wressT= ws + OFF_WRESST;
    const float* bress = ws + OFF_BRESS;
    float* ob = x1 + ((size_t)n * CO_ * T_ + t) * V_;
    for (int e = threadIdx.x; e < 128 * 25; e += 256) {
        int o = e / 25, v = e % 25;
        float a = bout[o];
#pragma unroll 8
        for (int hc = 0; hc < 192; ++hc) a += woutT[hc * 128 + o] * Tm[hc][v];
        float r = bress[o];
#pragma unroll 8
        for (int c = 0; c < 64; ++c) r += wressT[c * 128 + o] * Xs[c][v];
        ob[(size_t)o * T_ * V_ + v] = lrelu(a + r);
    }
}

// ---- K4: x2 = lrelu(bn(conv_ff(x1)) + bn(conv_ress(x))); emit transposed bf16 hi/lo ----
__global__ __launch_bounds__(256) void k4_x2(const float* __restrict__ x,
                                             const float* __restrict__ x1,
                                             const float* __restrict__ ws,
                                             unsigned short* __restrict__ x2hiT,
                                             unsigned short* __restrict__ x2loT)
{
    __shared__ float X1s[128][26];
    __shared__ float Xs[64][26];
    __shared__ float Res[128][26];
    int nt = blockIdx.x;
    int n = nt / T_, t = nt % T_;
    const float* xb = x + ((size_t)n * C_ * T_ + t) * V_;
    const float* x1b = x1 + ((size_t)n * CO_ * T_ + t) * V_;
    for (int e = threadIdx.x; e < 64 * 25; e += 256) {
        int c = e / 25, v = e % 25;
        Xs[c][v] = xb[(size_t)c * T_ * V_ + v];
    }
    for (int e = threadIdx.x; e < 128 * 25; e += 256) {
        int c = e / 25, v = e % 25;
        X1s[c][v] = x1b[(size_t)c * T_ * V_ + v];
    }
    __syncthreads();
    const float* wffT  = ws + OFF_WFFT;
    const float* bff   = ws + OFF_BFF;
    const float* wressT= ws + OFF_WRESST;
    const float* bress = ws + OFF_BRESS;
    for (int e = threadIdx.x; e < 128 * 25; e += 256) {
        int o = e / 25, v = e % 25;
        float a = bff[o];
#pragma unroll 8
        for (int c = 0; c < 128; ++c) a += wffT[c * 128 + o] * X1s[c][v];
        float r = bress[o];
#pragma unroll 8
        for (int c = 0; c < 64; ++c) r += wressT[c * 128 + o] * Xs[c][v];
        Res[o][v] = lrelu(a + r);
    }
    __syncthreads();
    // transposed write: x2T[n][col = t*25+v][o], bf16 hi + lo planes
    unsigned short* dhi = x2hiT + (size_t)n * 409600 + (size_t)t * 25 * 128;
    unsigned short* dlo = x2loT + (size_t)n * 409600 + (size_t)t * 25 * 128;
    for (int e = threadIdx.x; e < 128 * 25; e += 256) {
        int o = e & 127, v = e >> 7;
        float val = Res[o][v];
        unsigned short hi = f2bf_rne(val);
        float lo = val - bf2f(hi);
        dhi[v * 128 + o] = hi;
        dlo[v * 128 + o] = f2bf_rne(lo);
    }
}

// ---- K5: fused temporal(K=7)+rest conv as MFMA GEMM: M=128, N=3200/n, K=1024 ----
// out[o][col] = sum_{tap,i} A[tap*128+i][o] * x2T[col + 25*(tap-3)][i]  (tap 7: shift 0)
__global__ __launch_bounds__(256, 2) void k5_mfma(const unsigned short* __restrict__ wAhi,
                                                  const unsigned short* __restrict__ wAlo,
                                                  const unsigned short* __restrict__ x2hiT,
                                                  const unsigned short* __restrict__ x2loT,
                                                  const float* __restrict__ bcomb,
                                                  float* __restrict__ out)
{
    __shared__ unsigned short Ah[128][40];   // padded stride 80B
    __shared__ unsigned short Al[128][40];
    __shared__ unsigned short Bh[128][40];
    __shared__ unsigned short Bl[128][40];

    int blk = blockIdx.x;
    int n = blk / 25, ct = blk % 25;
    int c0 = ct * 128;
    int tid = threadIdx.x;
    int lane = tid & 63, wid = tid >> 6;
    int wm = wid & 1, wn = wid >> 1;

    const unsigned short* x2h_n = x2hiT + (size_t)n * 409600;
    const unsigned short* x2l_n = x2loT + (size_t)n * 409600;

    f32x4 acc[4][4];
#pragma unroll
    for (int a = 0; a < 4; ++a)
#pragma unroll
        for (int b = 0; b < 4; ++b) acc[a][b] = (f32x4)0.f;

    int rbase = lane & 15;
    int koff = (lane >> 4) * 8;

    for (int ks = 0; ks < 32; ++ks) {
        int tap = ks >> 2;
        int i0 = (ks & 3) * 32;
        int shift = (tap < 7) ? 25 * (tap - 3) : 0;
        __syncthreads();
        // stage A tile [o=0..127][kk=0..31] from wA[o*1024 + ks*32 + kk]
        for (int L = tid; L < 512; L += 256) {
            int o = L >> 2, g = (L & 3) * 8;
            *(ushort8*)&Ah[o][g] = *(const ushort8*)&wAhi[(size_t)o * 1024 + ks * 32 + g];
            *(ushort8*)&Al[o][g] = *(const ushort8*)&wAlo[(size_t)o * 1024 + ks * 32 + g];
        }
        // stage B tile [col=0..127][kk=0..31] from x2T[(c0+col+shift)*128 + i0 + kk]
        for (int L = tid; L < 512; L += 256) {
            int col = L >> 2, g = (L & 3) * 8;
            int cs = c0 + col + shift;
            ushort8 vh = (ushort8)0, vl = (ushort8)0;
            if (cs >= 0 && cs < 3200) {
                vh = *(const ushort8*)&x2h_n[(size_t)cs * 128 + i0 + g];
                vl = *(const ushort8*)&x2l_n[(size_t)cs * 128 + i0 + g];
            }
            *(ushort8*)&Bh[col][g] = vh;
            *(ushort8*)&Bl[col][g] = vl;
        }
        __syncthreads();
        short8 afh[4], afl[4], bfh[4], bfl[4];
#pragma unroll
        for (int mb = 0; mb < 4; ++mb) {
            int row = wm * 64 + mb * 16 + rbase;
            afh[mb] = *(const short8*)&Ah[row][koff];
            afl[mb] = *(const short8*)&Al[row][koff];
        }
#pragma unroll
        for (int nb = 0; nb < 4; ++nb) {
            int col = wn * 64 + nb * 16 + rbase;
            bfh[nb] = *(const short8*)&Bh[col][koff];
            bfl[nb] = *(const short8*)&Bl[col][koff];
        }
#pragma unroll
        for (int mb = 0; mb < 4; ++mb)
#pragma unroll
            for (int nb = 0; nb < 4; ++nb) {
                acc[mb][nb] = __builtin_amdgcn_mfma_f32_16x16x32_bf16(afh[mb], bfh[nb], acc[mb][nb], 0, 0, 0);
                acc[mb][nb] = __builtin_amdgcn_mfma_f32_16x16x32_bf16(afh[mb], bfl[nb], acc[mb][nb], 0, 0, 0);
                acc[mb][nb] = __builtin_amdgcn_mfma_f32_16x16x32_bf16(afl[mb], bfh[nb], acc[mb][nb], 0, 0, 0);
            }
    }
    // epilogue: C/D layout col=lane&15, row=(lane>>4)*4+r
#pragma unroll
    for (int mb = 0; mb < 4; ++mb) {
#pragma unroll
        for (int nb = 0; nb < 4; ++nb) {
            int col = c0 + wn * 64 + nb * 16 + (lane & 15);
#pragma unroll
            for (int r = 0; r < 4; ++r) {
                int o = wm * 64 + mb * 16 + (lane >> 4) * 4 + r;
                float y = acc[mb][nb][r] + bcomb[o];
                out[((size_t)n * 128 + o) * 3200 + col] = lrelu(y);
            }
        }
    }
}

extern "C" void kernel_launch(void* const* d_in, const int* in_sizes, int n_in,
                              void* d_out, int out_size, void* d_ws, size_t ws_size,
                              hipStream_t stream)
{
    const float* x       = (const float*)d_in[0];
    const float* w_qkv   = (const float*)d_in[1];
    const float* b_qkv   = (const float*)d_in[2];
    const float* values  = (const float*)d_in[3];
    const float* att_bias= (const float*)d_in[4];
    const float* w_out   = (const float*)d_in[5];
    const float* b_out   = (const float*)d_in[6];
    const float* g_out   = (const float*)d_in[7];
    const float* be_out  = (const float*)d_in[8];
    const float* m_out   = (const float*)d_in[9];
    const float* v_out   = (const float*)d_in[10];
    const float* w_ff    = (const float*)d_in[11];
    const float* b_ff    = (const float*)d_in[12];
    const float* g_ff    = (const float*)d_in[13];
    const float* be_ff   = (const float*)d_in[14];
    const float* m_ff    = (const float*)d_in[15];
    const float* v_ff    = (const float*)d_in[16];
    const float* w_t     = (const float*)d_in[17];
    const float* b_t     = (const float*)d_in[18];
    const float* g_t     = (const float*)d_in[19];
    const float* be_t    = (const float*)d_in[20];
    const float* m_t     = (const float*)d_in[21];
    const float* v_t     = (const float*)d_in[22];
    const float* w_ress  = (const float*)d_in[23];
    const float* b_ress  = (const float*)d_in[24];
    const float* g_ress  = (const float*)d_in[25];
    const float* be_ress = (const float*)d_in[26];
    const float* m_ress  = (const float*)d_in[27];
    const float* v_ress  = (const float*)d_in[28];
    const float* w_rest  = (const float*)d_in[29];
    const float* b_rest  = (const float*)d_in[30];
    const float* g_rest  = (const float*)d_in[31];
    const float* be_rest = (const float*)d_in[32];
    const float* m_rest  = (const float*)d_in[33];
    const float* v_rest  = (const float*)d_in[34];

    float* ws = (float*)d_ws;
    float* out = (float*)d_out;

    k0_prep<<<128, 256, 0, stream>>>(w_qkv,
        w_out, b_out, g_out, be_out, m_out, v_out,
        w_ff, b_ff, g_ff, be_ff, m_ff, v_ff,
        w_t, b_t, g_t, be_t, m_t, v_t,
        w_ress, b_ress, g_ress, be_ress, m_ress, v_ress,
        w_rest, b_rest, g_rest, be_rest, m_rest, v_rest,
        ws);
    k1_qkv<<<N_ * T_, 256, 0, stream>>>(x, b_qkv, ws, ws + OFF_QK);
    k2_att<<<N_ * H_, 256, 0, stream>>>(ws + OFF_QK, values, att_bias, ws + OFF_ATT);
    k3_x1<<<N_ * T_, 256, 0, stream>>>(x, ws + OFF_ATT, ws, out);
    k4_x2<<<N_ * T_, 256, 0, stream>>>(x, out, ws,
        (unsigned short*)(ws + OFF_X2HI), (unsigned short*)(ws + OFF_X2LO));
    k5_mfma<<<N_ * 25, 256, 0, stream>>>(
        (const unsigned short*)(ws + OFF_WAHI), (const unsigned short*)(ws + OFF_WALO),
        (const unsigned short*)(ws + OFF_X2HI), (const unsigned short*)(ws + OFF_X2LO),
        ws + OFF_BCOMB, out);
}

// Round 5
// 1299.078 us; speedup vs baseline: 5.0971x; 3.0888x over previous
//
#include <hip/hip_runtime.h>

#define N_  128
#define C_  64
#define T_  128
#define V_  25
#define CO_ 128
#define H_  3
#define D_  16

constexpr int COLS = 3200;
constexpr float EPSF = 1e-5f;

typedef __attribute__((ext_vector_type(8))) short short8;
typedef __attribute__((ext_vector_type(8))) unsigned short ushort8;
typedef __attribute__((ext_vector_type(4))) unsigned short us4v;
typedef __attribute__((ext_vector_type(4))) float f32x4;

// ---- workspace layout (float units) ----
constexpr size_t OFF_ATT  = 0;                          // 240,000
constexpr size_t OFF_XTHI = 240000;                     // 13,107,200 (26.2M ushorts)
constexpr size_t OFF_XTLO = OFF_XTHI + 13107200;
constexpr size_t OFF_BIG  = OFF_XTLO + 13107200;        // 78,643,200 floats, time-shared:
//   phase A: qk fp32 [n][96][3200]          (39,321,600 floats)
//   phase B: TmT hi at +0, lo at +39,321,600 (each 78,643,200 ushorts)
//   phase C: x2T hi at +0, lo at +26,214,400 (each 52,428,800 ushorts)
constexpr size_t BIGF     = 78643200;
constexpr size_t OFF_W    = OFF_BIG + BIGF;
constexpr size_t OFF_WQHI  = OFF_W;                     // 96*64 us = 3072 fl
constexpr size_t OFF_WQLO  = OFF_WQHI + 3072;
constexpr size_t OFF_WA3HI = OFF_WQLO + 3072;           // 128*256 us = 16384 fl
constexpr size_t OFF_WA3LO = OFF_WA3HI + 16384;
constexpr size_t OFF_WA4HI = OFF_WA3LO + 16384;         // 128*192 us = 12288 fl
constexpr size_t OFF_WA4LO = OFF_WA4HI + 12288;
constexpr size_t OFF_WA5HI = OFF_WA4LO + 12288;         // 128*1024 us = 65536 fl
constexpr size_t OFF_WA5LO = OFF_WA5HI + 65536;
constexpr size_t OFF_B3    = OFF_WA5LO + 65536;
constexpr size_t OFF_B4    = OFF_B3 + 128;
constexpr size_t OFF_B5    = OFF_B4 + 128;

__device__ __forceinline__ float lrelu(float y) { return y >= 0.f ? y : 0.1f * y; }

__device__ __forceinline__ unsigned short f2bf_rne(float f) {
    unsigned int u = __builtin_bit_cast(unsigned int, f);
    u += 0x7FFFu + ((u >> 16) & 1u);
    return (unsigned short)(u >> 16);
}
__device__ __forceinline__ float bf2f(unsigned short b) {
    unsigned int u = ((unsigned int)b) << 16;
    return __builtin_bit_cast(float, u);
}

// ---- K0: BN-fold + build all bf16 hi/lo A-operands ----
__global__ void k0_prep(const float* __restrict__ w_qkv,
                        const float* __restrict__ w_out, const float* __restrict__ b_out,
                        const float* __restrict__ g_out, const float* __restrict__ be_out,
                        const float* __restrict__ m_out, const float* __restrict__ v_out,
                        const float* __restrict__ w_ff,  const float* __restrict__ b_ff,
                        const float* __restrict__ g_ff,  const float* __restrict__ be_ff,
                        const float* __restrict__ m_ff,  const float* __restrict__ v_ff,
                        const float* __restrict__ w_t,   const float* __restrict__ b_t,
                        const float* __restrict__ g_t,   const float* __restrict__ be_t,
                        const float* __restrict__ m_t,   const float* __restrict__ v_t,
                        const float* __restrict__ w_ress,const float* __restrict__ b_ress,
                        const float* __restrict__ g_ress,const float* __restrict__ be_ress,
                        const float* __restrict__ m_ress,const float* __restrict__ v_ress,
                        const float* __restrict__ w_rest,const float* __restrict__ b_rest,
                        const float* __restrict__ g_rest,const float* __restrict__ be_rest,
                        const float* __restrict__ m_rest,const float* __restrict__ v_rest,
                        float* __restrict__ ws)
{
    int tid = blockIdx.x * blockDim.x + threadIdx.x;
    int np = gridDim.x * blockDim.x;

    unsigned short* wqh = (unsigned short*)(ws + OFF_WQHI);
    unsigned short* wql = (unsigned short*)(ws + OFF_WQLO);
    for (int idx = tid; idx < 96 * 64; idx += np) {
        float val = w_qkv[idx];
        unsigned short hi = f2bf_rne(val);
        wqh[idx] = hi;
        wql[idx] = f2bf_rne(val - bf2f(hi));
    }

    unsigned short* w3h = (unsigned short*)(ws + OFF_WA3HI);
    unsigned short* w3l = (unsigned short*)(ws + OFF_WA3LO);
    for (int idx = tid; idx < 128 * 256; idx += np) {
        int o = idx >> 8, k = idx & 255;
        float val;
        if (k < 192) {
            float sc = g_out[o] * rsqrtf(v_out[o] + EPSF);
            val = w_out[o * 192 + k] * sc;
        } else {
            float sc = g_ress[o] * rsqrtf(v_ress[o] + EPSF);
            val = w_ress[o * 64 + (k - 192)] * sc;
        }
        unsigned short hi = f2bf_rne(val);
        w3h[idx] = hi;
        w3l[idx] = f2bf_rne(val - bf2f(hi));
    }

    unsigned short* w4h = (unsigned short*)(ws + OFF_WA4HI);
    unsigned short* w4l = (unsigned short*)(ws + OFF_WA4LO);
    for (int idx = tid; idx < 128 * 192; idx += np) {
        int o = idx / 192, k = idx % 192;
        float val;
        if (k < 128) {
            float sc = g_ff[o] * rsqrtf(v_ff[o] + EPSF);
            val = w_ff[o * 128 + k] * sc;
        } else {
            float sc = g_ress[o] * rsqrtf(v_ress[o] + EPSF);
            val = w_ress[o * 64 + (k - 128)] * sc;
        }
        unsigned short hi = f2bf_rne(val);
        w4h[idx] = hi;
        w4l[idx] = f2bf_rne(val - bf2f(hi));
    }

    unsigned short* w5h = (unsigned short*)(ws + OFF_WA5HI);
    unsigned short* w5l = (unsigned short*)(ws + OFF_WA5LO);
    for (int idx = tid; idx < 128 * 1024; idx += np) {
        int o = idx >> 10, kk = idx & 1023;
        int tap = kk >> 7, i = kk & 127;
        float val;
        if (tap < 7) {
            float sc = g_t[o] * rsqrtf(v_t[o] + EPSF);
            val = w_t[((size_t)o * 128 + i) * 7 + tap] * sc;
        } else {
            float sc = g_rest[o] * rsqrtf(v_rest[o] + EPSF);
            val = w_rest[o * 128 + i] * sc;
        }
        unsigned short hi = f2bf_rne(val);
        w5h[idx] = hi;
        w5l[idx] = f2bf_rne(val - bf2f(hi));
    }

    for (int o = tid; o < 128; o += np) {
        float sco = g_out[o] * rsqrtf(v_out[o] + EPSF);
        float scr = g_ress[o] * rsqrtf(v_ress[o] + EPSF);
        float scf = g_ff[o] * rsqrtf(v_ff[o] + EPSF);
        float sct = g_t[o] * rsqrtf(v_t[o] + EPSF);
        float sce = g_rest[o] * rsqrtf(v_rest[o] + EPSF);
        float bres = (b_ress[o] - m_ress[o]) * scr + be_ress[o];
        ws[OFF_B3 + o] = (b_out[o] - m_out[o]) * sco + be_out[o] + bres;
        ws[OFF_B4 + o] = (b_ff[o] - m_ff[o]) * scf + be_ff[o] + bres;
        ws[OFF_B5 + o] = (b_t[o] - m_t[o]) * sct + be_t[o]
                       + (b_rest[o] - m_rest[o]) * sce + be_rest[o];
    }
}

// ---- k_xt: x[n][c][t][v] -> xT[n][col][64] bf16 hi/lo ----
__global__ __launch_bounds__(256) void k_xt(const float* __restrict__ x,
                                            unsigned short* __restrict__ xthi,
                                            unsigned short* __restrict__ xtlo)
{
    __shared__ float Xs[64][26];
    int nt = blockIdx.x;
    int n = nt >> 7, t = nt & 127;
    const float* xb = x + ((size_t)n * C_ * T_ + t) * V_;
    for (int e = threadIdx.x; e < 1600; e += 256) {
        int c = e / 25, u = e % 25;
        Xs[c][u] = xb[(size_t)c * (T_ * V_) + u];
    }
    __syncthreads();
    unsigned short* dh = xthi + ((size_t)n * COLS + t * 25) * 64;
    unsigned short* dl = xtlo + ((size_t)n * COLS + t * 25) * 64;
    for (int e = threadIdx.x; e < 1600; e += 256) {
        int v = e >> 6, c = e & 63;
        float val = Xs[c][v];
        unsigned short hi = f2bf_rne(val);
        dh[(size_t)v * 64 + c] = hi;
        dl[(size_t)v * 64 + c] = f2bf_rne(val - bf2f(hi));
    }
}

// ---- k1: qkv GEMM M=96,K=64 -> qk fp32 [n][96][3200] ----
__global__ __launch_bounds__(256, 2) void k1_mfma(const unsigned short* __restrict__ wqh,
                                                   const unsigned short* __restrict__ wql,
                                                   const unsigned short* __restrict__ xthi,
                                                   const unsigned short* __restrict__ xtlo,
                                                   const float* __restrict__ b_qkv,
                                                   float* __restrict__ qk)
{
    __shared__ unsigned short Ah[96][40], Al[96][40], Bh[128][40], Bl[128][40];
    int blk = blockIdx.x;
    int n = blk / 25, ct = blk % 25;
    int c0 = ct * 128;
    int tid = threadIdx.x, lane = tid & 63, wid = tid >> 6;
    int wm = wid & 1, wn = wid >> 1;
    const unsigned short* xh = xthi + (size_t)n * COLS * 64;
    const unsigned short* xl = xtlo + (size_t)n * COLS * 64;
    f32x4 acc[3][4];
#pragma unroll
    for (int a = 0; a < 3; ++a)
#pragma unroll
        for (int b = 0; b < 4; ++b) acc[a][b] = (f32x4)0.f;
    int rbase = lane & 15, koff = (lane >> 4) * 8;

    for (int ks = 0; ks < 2; ++ks) {
        __syncthreads();
        for (int L = tid; L < 384; L += 256) {
            int o = L >> 2, g = (L & 3) * 8;
            *(ushort8*)&Ah[o][g] = *(const ushort8*)&wqh[(size_t)o * 64 + ks * 32 + g];
            *(ushort8*)&Al[o][g] = *(const ushort8*)&wql[(size_t)o * 64 + ks * 32 + g];
        }
        for (int L = tid; L < 512; L += 256) {
            int col = L >> 2, g = (L & 3) * 8;
            size_t src = (size_t)(c0 + col) * 64 + ks * 32 + g;
            *(ushort8*)&Bh[col][g] = *(const ushort8*)&xh[src];
            *(ushort8*)&Bl[col][g] = *(const ushort8*)&xl[src];
        }
        __syncthreads();
        short8 afh[3], afl[3], bfh[4], bfl[4];
#pragma unroll
        for (int mb = 0; mb < 3; ++mb) {
            int row = wm * 48 + mb * 16 + rbase;
            afh[mb] = *(const short8*)&Ah[row][koff];
            afl[mb] = *(const short8*)&Al[row][koff];
        }
#pragma unroll
        for (int nb = 0; nb < 4; ++nb) {
            int col = wn * 64 + nb * 16 + rbase;
            bfh[nb] = *(const short8*)&Bh[col][koff];
            bfl[nb] = *(const short8*)&Bl[col][koff];
        }
#pragma unroll
        for (int mb = 0; mb < 3; ++mb)
#pragma unroll
            for (int nb = 0; nb < 4; ++nb) {
                acc[mb][nb] = __builtin_amdgcn_mfma_f32_16x16x32_bf16(afh[mb], bfh[nb], acc[mb][nb], 0, 0, 0);
                acc[mb][nb] = __builtin_amdgcn_mfma_f32_16x16x32_bf16(afh[mb], bfl[nb], acc[mb][nb], 0, 0, 0);
                acc[mb][nb] = __builtin_amdgcn_mfma_f32_16x16x32_bf16(afl[mb], bfh[nb], acc[mb][nb], 0, 0, 0);
            }
    }
#pragma unroll
    for (int mb = 0; mb < 3; ++mb) {
#pragma unroll
        for (int nb = 0; nb < 4; ++nb) {
            int col = c0 + wn * 64 + nb * 16 + (lane & 15);
#pragma unroll
            for (int r = 0; r < 4; ++r) {
                int o = wm * 48 + mb * 16 + (lane >> 4) * 4 + r;
                qk[((size_t)n * 96 + o) * COLS + col] = acc[mb][nb][r] + b_qkv[o];
            }
        }
    }
}

// ---- k2: attention logits + softmax -> att[n,h,u,v] ----
__global__ __launch_bounds__(256) void k2_att(const float* __restrict__ qk,
                                              const float* __restrict__ values,
                                              const float* __restrict__ att_bias,
                                              float* __restrict__ att)
{
    int nh = blockIdx.x;
    int n = nh / H_, h = nh % H_;
    __shared__ float Qs[D_][8][26];
    __shared__ float Ks[D_][8][26];
    __shared__ float L[V_][V_ + 1];
    float acc[3] = {0.f, 0.f, 0.f};
    const float* qbase = qk + ((size_t)(n * 96 + h * 16) * T_) * V_;
    const float* kbase = qk + ((size_t)(n * 96 + 48 + h * 16) * T_) * V_;
    for (int tc = 0; tc < T_; tc += 8) {
        __syncthreads();
        for (int e = threadIdx.x; e < 16 * 8 * 25; e += 256) {
            int d = e / 200, r = e % 200;
            int tt = r / 25, u = r % 25;
            Qs[d][tt][u] = qbase[((size_t)d * T_ + tc + tt) * V_ + u];
            Ks[d][tt][u] = kbase[((size_t)d * T_ + tc + tt) * V_ + u];
        }
        __syncthreads();
#pragma unroll
        for (int p = 0; p < 3; ++p) {
            int e = threadIdx.x + p * 256;
            if (e < 625) {
                int u = e / 25, v = e % 25;
                float a = acc[p];
                for (int tt = 0; tt < 8; ++tt) {
#pragma unroll
                    for (int d = 0; d < 16; ++d)
                        a += Qs[d][tt][u] * Ks[d][tt][v];
                }
                acc[p] = a;
            }
        }
    }
    float scale = values[h] / 2048.0f;
    float bias = att_bias[h];
#pragma unroll
    for (int p = 0; p < 3; ++p) {
        int e = threadIdx.x + p * 256;
        if (e < 625) L[e / 25][e % 25] = acc[p] * scale + bias;
    }
    __syncthreads();
    if (threadIdx.x < 25) {
        int u = threadIdx.x;
        float m = -1e30f;
        for (int v = 0; v < 25; ++v) m = fmaxf(m, L[u][v]);
        float ex[25];
        float s = 0.f;
        for (int v = 0; v < 25; ++v) { ex[v] = expf(L[u][v] - m); s += ex[v]; }
        float inv = 1.0f / s;
        float* ab = att + ((size_t)(n * 3 + h) * 25 + u) * 25;
        for (int v = 0; v < 25; ++v) ab[v] = ex[v] * inv;
    }
}

// ---- k_tm: Tm[hc][t,v] = sum_u x[c][t,u]*att[h][u][v] -> TmT[n][col][192] hi/lo ----
__global__ __launch_bounds__(256) void k_tm(const float* __restrict__ x,
                                            const float* __restrict__ att,
                                            unsigned short* __restrict__ tmhi,
                                            unsigned short* __restrict__ tmlo)
{
    __shared__ float Xs[64][26];
    __shared__ float As[3][25][26];
    int nt = blockIdx.x;
    int n = nt >> 7, t = nt & 127;
    const float* xb = x + ((size_t)n * C_ * T_ + t) * V_;
    for (int e = threadIdx.x; e < 1600; e += 256) {
        int c = e / 25, u = e % 25;
        Xs[c][u] = xb[(size_t)c * (T_ * V_) + u];
    }
    const float* ab = att + (size_t)n * 3 * 625;
    for (int e = threadIdx.x; e < 1875; e += 256) {
        int h = e / 625, r = e % 625;
        As[h][r / 25][r % 25] = ab[e];
    }
    __syncthreads();
    unsigned short* dh = tmhi + ((size_t)n * COLS + t * 25) * 192;
    unsigned short* dl = tmlo + ((size_t)n * COLS + t * 25) * 192;
    for (int e = threadIdx.x; e < 4800; e += 256) {
        int v = e / 192, hc = e % 192;
        int h = hc >> 6, c = hc & 63;
        float a = 0.f;
#pragma unroll
        for (int u = 0; u < 25; ++u) a += Xs[c][u] * As[h][u][v];
        unsigned short hi = f2bf_rne(a);
        dh[(size_t)v * 192 + hc] = hi;
        dl[(size_t)v * 192 + hc] = f2bf_rne(a - bf2f(hi));
    }
}

// ---- k3: x1 GEMM M=128,K=256 (192 Tm + 64 x) -> x1T hi/lo (in d_out) ----
__global__ __launch_bounds__(256, 2) void k3_mfma(const unsigned short* __restrict__ w3h,
                                                   const unsigned short* __restrict__ w3l,
                                                   const unsigned short* __restrict__ tmhi,
                                                   const unsigned short* __restrict__ tmlo,
                                                   const unsigned short* __restrict__ xthi,
                                                   const unsigned short* __restrict__ xtlo,
                                                   const float* __restrict__ b3,
                                                   unsigned short* __restrict__ x1hi,
                                                   unsigned short* __restrict__ x1lo)
{
    __shared__ unsigned short Ah[128][40], Al[128][40], Bh[128][40], Bl[128][40];
    int blk = blockIdx.x;
    int n = blk / 25, ct = blk % 25;
    int c0 = ct * 128;
    int tid = threadIdx.x, lane = tid & 63, wid = tid >> 6;
    int wm = wid & 1, wn = wid >> 1;
    const unsigned short* th = tmhi + (size_t)n * COLS * 192;
    const unsigned short* tl = tmlo + (size_t)n * COLS * 192;
    const unsigned short* xh = xthi + (size_t)n * COLS * 64;
    const unsigned short* xl = xtlo + (size_t)n * COLS * 64;
    f32x4 acc[4][4];
#pragma unroll
    for (int a = 0; a < 4; ++a)
#pragma unroll
        for (int b = 0; b < 4; ++b) acc[a][b] = (f32x4)0.f;
    int rbase = lane & 15, koff = (lane >> 4) * 8;

    for (int ks = 0; ks < 8; ++ks) {
        __syncthreads();
        for (int L = tid; L < 512; L += 256) {
            int o = L >> 2, g = (L & 3) * 8;
            *(ushort8*)&Ah[o][g] = *(const ushort8*)&w3h[(size_t)o * 256 + ks * 32 + g];
            *(ushort8*)&Al[o][g] = *(const ushort8*)&w3l[(size_t)o * 256 + ks * 32 + g];
        }
        for (int L = tid; L < 512; L += 256) {
            int col = L >> 2, g = (L & 3) * 8;
            ushort8 vh, vl;
            if (ks < 6) {
                size_t src = (size_t)(c0 + col) * 192 + ks * 32 + g;
                vh = *(const ushort8*)&th[src];
                vl = *(const ushort8*)&tl[src];
            } else {
                size_t src = (size_t)(c0 + col) * 64 + (ks - 6) * 32 + g;
                vh = *(const ushort8*)&xh[src];
                vl = *(const ushort8*)&xl[src];
            }
            *(ushort8*)&Bh[col][g] = vh;
            *(ushort8*)&Bl[col][g] = vl;
        }
        __syncthreads();
        short8 afh[4], afl[4], bfh[4], bfl[4];
#pragma unroll
        for (int mb = 0; mb < 4; ++mb) {
            int row = wm * 64 + mb * 16 + rbase;
            afh[mb] = *(const short8*)&Ah[row][koff];
            afl[mb] = *(const short8*)&Al[row][koff];
        }
#pragma unroll
        for (int nb = 0; nb < 4; ++nb) {
            int col = wn * 64 + nb * 16 + rbase;
            bfh[nb] = *(const short8*)&Bh[col][koff];
            bfl[nb] = *(const short8*)&Bl[col][koff];
        }
#pragma unroll
        for (int mb = 0; mb < 4; ++mb)
#pragma unroll
            for (int nb = 0; nb < 4; ++nb) {
                acc[mb][nb] = __builtin_amdgcn_mfma_f32_16x16x32_bf16(afh[mb], bfh[nb], acc[mb][nb], 0, 0, 0);
                acc[mb][nb] = __builtin_amdgcn_mfma_f32_16x16x32_bf16(afh[mb], bfl[nb], acc[mb][nb], 0, 0, 0);
                acc[mb][nb] = __builtin_amdgcn_mfma_f32_16x16x32_bf16(afl[mb], bfh[nb], acc[mb][nb], 0, 0, 0);
            }
    }
#pragma unroll
    for (int mb = 0; mb < 4; ++mb) {
#pragma unroll
        for (int nb = 0; nb < 4; ++nb) {
            int col = c0 + wn * 64 + nb * 16 + (lane & 15);
            int obase = wm * 64 + mb * 16 + (lane >> 4) * 4;
            us4v hv, lv;
#pragma unroll
            for (int r = 0; r < 4; ++r) {
                float y = lrelu(acc[mb][nb][r] + b3[obase + r]);
                unsigned short hi = f2bf_rne(y);
                hv[r] = hi;
                lv[r] = f2bf_rne(y - bf2f(hi));
            }
            size_t dst = ((size_t)n * COLS + col) * 128 + obase;
            *(us4v*)&x1hi[dst] = hv;
            *(us4v*)&x1lo[dst] = lv;
        }
    }
}

// ---- k4: x2 GEMM M=128,K=192 (128 x1 + 64 x) -> x2T hi/lo ----
__global__ __launch_bounds__(256, 2) void k4_mfma(const unsigned short* __restrict__ w4h,
                                                   const unsigned short* __restrict__ w4l,
                                                   const unsigned short* __restrict__ x1hi,
                                                   const unsigned short* __restrict__ x1lo,
                                                   const unsigned short* __restrict__ xthi,
                                                   const unsigned short* __restrict__ xtlo,
                                                   const float* __restrict__ b4,
                                                   unsigned short* __restrict__ x2hi,
                                                   unsigned short* __restrict__ x2lo)
{
    __shared__ unsigned short Ah[128][40], Al[128][40], Bh[128][40], Bl[128][40];
    int blk = blockIdx.x;
    int n = blk / 25, ct = blk % 25;
    int c0 = ct * 128;
    int tid = threadIdx.x, lane = tid & 63, wid = tid >> 6;
    int wm = wid & 1, wn = wid >> 1;
    const unsigned short* ph = x1hi + (size_t)n * COLS * 128;
    const unsigned short* pl = x1lo + (size_t)n * COLS * 128;
    const unsigned short* xh = xthi + (size_t)n * COLS * 64;
    const unsigned short* xl = xtlo + (size_t)n * COLS * 64;
    f32x4 acc[4][4];
#pragma unroll
    for (int a = 0; a < 4; ++a)
#pragma unroll
        for (int b = 0; b < 4; ++b) acc[a][b] = (f32x4)0.f;
    int rbase = lane & 15, koff = (lane >> 4) * 8;

    for (int ks = 0; ks < 6; ++ks) {
        __syncthreads();
        for (int L = tid; L < 512; L += 256) {
            int o = L >> 2, g = (L & 3) * 8;
            *(ushort8*)&Ah[o][g] = *(const ushort8*)&w4h[(size_t)o * 192 + ks * 32 + g];
            *(ushort8*)&Al[o][g] = *(const ushort8*)&w4l[(size_t)o * 192 + ks * 32 + g];
        }
        for (int L = tid; L < 512; L += 256) {
            int col = L >> 2, g = (L & 3) * 8;
            ushort8 vh, vl;
            if (ks < 4) {
                size_t src = (size_t)(c0 + col) * 128 + ks * 32 + g;
                vh = *(const ushort8*)&ph[src];
                vl = *(const ushort8*)&pl[src];
            } else {
                size_t src = (size_t)(c0 + col) * 64 + (ks - 4) * 32 + g;
                vh = *(const ushort8*)&xh[src];
                vl = *(const ushort8*)&xl[src];
            }
            *(ushort8*)&Bh[col][g] = vh;
            *(ushort8*)&Bl[col][g] = vl;
        }
        __syncthreads();
        short8 afh[4], afl[4], bfh[4], bfl[4];
#pragma unroll
        for (int mb = 0; mb < 4; ++mb) {
            int row = wm * 64 + mb * 16 + rbase;
            afh[mb] = *(const short8*)&Ah[row][koff];
            afl[mb] = *(const short8*)&Al[row][koff];
        }
#pragma unroll
        for (int nb = 0; nb < 4; ++nb) {
            int col = wn * 64 + nb * 16 + rbase;
            bfh[nb] = *(const short8*)&Bh[col][koff];
            bfl[nb] = *(const short8*)&Bl[col][koff];
        }
#pragma unroll
        for (int mb = 0; mb < 4; ++mb)
#pragma unroll
            for (int nb = 0; nb < 4; ++nb) {
                acc[mb][nb] = __builtin_amdgcn_mfma_f32_16x16x32_bf16(afh[mb], bfh[nb], acc[mb][nb], 0, 0, 0);
                acc[mb][nb] = __builtin_amdgcn_mfma_f32_16x16x32_bf16(afh[mb], bfl[nb], acc[mb][nb], 0, 0, 0);
                acc[mb][nb] = __builtin_amdgcn_mfma_f32_16x16x32_bf16(afl[mb], bfh[nb], acc[mb][nb], 0, 0, 0);
            }
    }
#pragma unroll
    for (int mb = 0; mb < 4; ++mb) {
#pragma unroll
        for (int nb = 0; nb < 4; ++nb) {
            int col = c0 + wn * 64 + nb * 16 + (lane & 15);
            int obase = wm * 64 + mb * 16 + (lane >> 4) * 4;
            us4v hv, lv;
#pragma unroll
            for (int r = 0; r < 4; ++r) {
                float y = lrelu(acc[mb][nb][r] + b4[obase + r]);
                unsigned short hi = f2bf_rne(y);
                hv[r] = hi;
                lv[r] = f2bf_rne(y - bf2f(hi));
            }
            size_t dst = ((size_t)n * COLS + col) * 128 + obase;
            *(us4v*)&x2hi[dst] = hv;
            *(us4v*)&x2lo[dst] = lv;
        }
    }
}

// ---- k5: fused temporal(K=7)+rest conv GEMM M=128,K=1024 -> out fp32 ----
__global__ __launch_bounds__(256, 2) void k5_mfma(const unsigned short* __restrict__ wAhi,
                                                  const unsigned short* __restrict__ wAlo,
                                                  const unsigned short* __restrict__ x2hiT,
                                                  const unsigned short* __restrict__ x2loT,
                                                  const float* __restrict__ bcomb,
                                                  float* __restrict__ out)
{
    __shared__ unsigned short Ah[128][40];
    __shared__ unsigned short Al[128][40];
    __shared__ unsigned short Bh[128][40];
    __shared__ unsigned short Bl[128][40];

    int blk = blockIdx.x;
    int n = blk / 25, ct = blk % 25;
    int c0 = ct * 128;
    int tid = threadIdx.x;
    int lane = tid & 63, wid = tid >> 6;
    int wm = wid & 1, wn = wid >> 1;

    const unsigned short* x2h_n = x2hiT + (size_t)n * 409600;
    const unsigned short* x2l_n = x2loT + (size_t)n * 409600;

    f32x4 acc[4][4];
#pragma unroll
    for (int a = 0; a < 4; ++a)
#pragma unroll
        for (int b = 0; b < 4; ++b) acc[a][b] = (f32x4)0.f;

    int rbase = lane & 15;
    int koff = (lane >> 4) * 8;

    for (int ks = 0; ks < 32; ++ks) {
        int tap = ks >> 2;
        int i0 = (ks & 3) * 32;
        int shift = (tap < 7) ? 25 * (tap - 3) : 0;
        __syncthreads();
        for (int L = tid; L < 512; L += 256) {
            int o = L >> 2, g = (L & 3) * 8;
            *(ushort8*)&Ah[o][g] = *(const ushort8*)&wAhi[(size_t)o * 1024 + ks * 32 + g];
            *(ushort8*)&Al[o][g] = *(const ushort8*)&wAlo[(size_t)o * 1024 + ks * 32 + g];
        }
        for (int L = tid; L < 512; L += 256) {
            int col = L >> 2, g = (L & 3) * 8;
            int cs = c0 + col + shift;
            ushort8 vh = (ushort8)0, vl = (ushort8)0;
            if (cs >= 0 && cs < 3200) {
                vh = *(const ushort8*)&x2h_n[(size_t)cs * 128 + i0 + g];
                vl = *(const ushort8*)&x2l_n[(size_t)cs * 128 + i0 + g];
            }
            *(ushort8*)&Bh[col][g] = vh;
            *(ushort8*)&Bl[col][g] = vl;
        }
        __syncthreads();
        short8 afh[4], afl[4], bfh[4], bfl[4];
#pragma unroll
        for (int mb = 0; mb < 4; ++mb) {
            int row = wm * 64 + mb * 16 + rbase;
            afh[mb] = *(const short8*)&Ah[row][koff];
            afl[mb] = *(const short8*)&Al[row][koff];
        }
#pragma unroll
        for (int nb = 0; nb < 4; ++nb) {
            int col = wn * 64 + nb * 16 + rbase;
            bfh[nb] = *(const short8*)&Bh[col][koff];
            bfl[nb] = *(const short8*)&Bl[col][koff];
        }
#pragma unroll
        for (int mb = 0; mb < 4; ++mb)
#pragma unroll
            for (int nb = 0; nb < 4; ++nb) {
                acc[mb][nb] = __builtin_amdgcn_mfma_f32_16x16x32_bf16(afh[mb], bfh[nb], acc[mb][nb], 0, 0, 0);
                acc[mb][nb] = __builtin_amdgcn_mfma_f32_16x16x32_bf16(afh[mb], bfl[nb], acc[mb][nb], 0, 0, 0);
                acc[mb][nb] = __builtin_amdgcn_mfma_f32_16x16x32_bf16(afl[mb], bfh[nb], acc[mb][nb], 0, 0, 0);
            }
    }
#pragma unroll
    for (int mb = 0; mb < 4; ++mb) {
#pragma unroll
        for (int nb = 0; nb < 4; ++nb) {
            int col = c0 + wn * 64 + nb * 16 + (lane & 15);
#pragma unroll
            for (int r = 0; r < 4; ++r) {
                int o = wm * 64 + mb * 16 + (lane >> 4) * 4 + r;
                float y = acc[mb][nb][r] + bcomb[o];
                out[((size_t)n * 128 + o) * 3200 + col] = lrelu(y);
            }
        }
    }
}

extern "C" void kernel_launch(void* const* d_in, const int* in_sizes, int n_in,
                              void* d_out, int out_size, void* d_ws, size_t ws_size,
                              hipStream_t stream)
{
    const float* x       = (const float*)d_in[0];
    const float* w_qkv   = (const float*)d_in[1];
    const float* b_qkv   = (const float*)d_in[2];
    const float* values  = (const float*)d_in[3];
    const float* att_bias= (const float*)d_in[4];
    const float* w_out   = (const float*)d_in[5];
    const float* b_out   = (const float*)d_in[6];
    const float* g_out   = (const float*)d_in[7];
    const float* be_out  = (const float*)d_in[8];
    const float* m_out   = (const float*)d_in[9];
    const float* v_out   = (const float*)d_in[10];
    const float* w_ff    = (const float*)d_in[11];
    const float* b_ff    = (const float*)d_in[12];
    const float* g_ff    = (const float*)d_in[13];
    const float* be_ff   = (const float*)d_in[14];
    const float* m_ff    = (const float*)d_in[15];
    const float* v_ff    = (const float*)d_in[16];
    const float* w_t     = (const float*)d_in[17];
    const float* b_t     = (const float*)d_in[18];
    const float* g_t     = (const float*)d_in[19];
    const float* be_t    = (const float*)d_in[20];
    const float* m_t     = (const float*)d_in[21];
    const float* v_t     = (const float*)d_in[22];
    const float* w_ress  = (const float*)d_in[23];
    const float* b_ress  = (const float*)d_in[24];
    const float* g_ress  = (const float*)d_in[25];
    const float* be_ress = (const float*)d_in[26];
    const float* m_ress  = (const float*)d_in[27];
    const float* v_ress  = (const float*)d_in[28];
    const float* w_rest  = (const float*)d_in[29];
    const float* b_rest  = (const float*)d_in[30];
    const float* g_rest  = (const float*)d_in[31];
    const float* be_rest = (const float*)d_in[32];
    const float* m_rest  = (const float*)d_in[33];
    const float* v_rest  = (const float*)d_in[34];

    float* ws = (float*)d_ws;
    float* out = (float*)d_out;

    unsigned short* xthi = (unsigned short*)(ws + OFF_XTHI);
    unsigned short* xtlo = (unsigned short*)(ws + OFF_XTLO);
    float*          qk   = ws + OFF_BIG;
    unsigned short* tmhi = (unsigned short*)(ws + OFF_BIG);
    unsigned short* tmlo = (unsigned short*)(ws + OFF_BIG + 39321600);
    unsigned short* x2hi = (unsigned short*)(ws + OFF_BIG);
    unsigned short* x2lo = (unsigned short*)(ws + OFF_BIG + 26214400);
    unsigned short* x1hi = (unsigned short*)out;
    unsigned short* x1lo = x1hi + 52428800;

    k0_prep<<<128, 256, 0, stream>>>(w_qkv,
        w_out, b_out, g_out, be_out, m_out, v_out,
        w_ff, b_ff, g_ff, be_ff, m_ff, v_ff,
        w_t, b_t, g_t, be_t, m_t, v_t,
        w_ress, b_ress, g_ress, be_ress, m_ress, v_ress,
        w_rest, b_rest, g_rest, be_rest, m_rest, v_rest,
        ws);
    k_xt<<<N_ * T_, 256, 0, stream>>>(x, xthi, xtlo);
    k1_mfma<<<N_ * 25, 256, 0, stream>>>(
        (const unsigned short*)(ws + OFF_WQHI), (const unsigned short*)(ws + OFF_WQLO),
        xthi, xtlo, b_qkv, qk);
    k2_att<<<N_ * H_, 256, 0, stream>>>(qk, values, att_bias, ws + OFF_ATT);
    k_tm<<<N_ * T_, 256, 0, stream>>>(x, ws + OFF_ATT, tmhi, tmlo);
    k3_mfma<<<N_ * 25, 256, 0, stream>>>(
        (const unsigned short*)(ws + OFF_WA3HI), (const unsigned short*)(ws + OFF_WA3LO),
        tmhi, tmlo, xthi, xtlo, ws + OFF_B3, x1hi, x1lo);
    k4_mfma<<<N_ * 25, 256, 0, stream>>>(
        (const unsigned short*)(ws + OFF_WA4HI), (const unsigned short*)(ws + OFF_WA4LO),
        x1hi, x1lo, xthi, xtlo, ws + OFF_B4, x2hi, x2lo);
    k5_mfma<<<N_ * 25, 256, 0, stream>>>(
        (const unsigned short*)(ws + OFF_WA5HI), (const unsigned short*)(ws + OFF_WA5LO),
        x2hi, x2lo, ws + OFF_B5, out);
}

// Round 6
// 1266.518 us; speedup vs baseline: 5.2281x; 1.0257x over previous
//
#include <hip/hip_runtime.h>

#define N_  128
#define C_  64
#define T_  128
#define V_  25
#define CO_ 128
#define H_  3
#define D_  16

constexpr int COLS = 3200;
constexpr float EPSF = 1e-5f;

typedef __attribute__((ext_vector_type(8))) short short8;
typedef __attribute__((ext_vector_type(8))) unsigned short ushort8;
typedef __attribute__((ext_vector_type(4))) unsigned short us4v;
typedef __attribute__((ext_vector_type(4))) float f32x4;

// ---- workspace layout (float units) ----
constexpr size_t OFF_ATT  = 0;                          // 240,000
constexpr size_t OFF_XTHI = 240000;                     // 13,107,200 (26.2M ushorts)
constexpr size_t OFF_XTLO = OFF_XTHI + 13107200;
constexpr size_t OFF_BIG  = OFF_XTLO + 13107200;        // 78,643,200 floats, time-shared:
//   phase A: qk bf16 [n][96][3200] (39.3M ushorts = 19.7M floats) + part @ +20M floats
//   phase B: TmT hi at +0, lo at +39,321,600 (each 78,643,200 ushorts)
//   phase C: x2T hi at +0, lo at +26,214,400 (each 52,428,800 ushorts)
constexpr size_t BIGF     = 78643200;
constexpr size_t OFF_PART = OFF_BIG + 20000000;         // 960,000 floats (4*384*625)
constexpr size_t OFF_W    = OFF_BIG + BIGF;
constexpr size_t OFF_WQHI  = OFF_W;                     // 96*64 us = 3072 fl
constexpr size_t OFF_WQLO  = OFF_WQHI + 3072;
constexpr size_t OFF_WA3HI = OFF_WQLO + 3072;           // 128*256 us = 16384 fl
constexpr size_t OFF_WA3LO = OFF_WA3HI + 16384;
constexpr size_t OFF_WA4HI = OFF_WA3LO + 16384;         // 128*192 us = 12288 fl
constexpr size_t OFF_WA4LO = OFF_WA4HI + 12288;
constexpr size_t OFF_WA5HI = OFF_WA4LO + 12288;         // 128*1024 us = 65536 fl
constexpr size_t OFF_WA5LO = OFF_WA5HI + 65536;
constexpr size_t OFF_B3    = OFF_WA5LO + 65536;
constexpr size_t OFF_B4    = OFF_B3 + 128;
constexpr size_t OFF_B5    = OFF_B4 + 128;

__device__ __forceinline__ float lrelu(float y) { return y >= 0.f ? y : 0.1f * y; }

__device__ __forceinline__ unsigned short f2bf_rne(float f) {
    unsigned int u = __builtin_bit_cast(unsigned int, f);
    u += 0x7FFFu + ((u >> 16) & 1u);
    return (unsigned short)(u >> 16);
}
__device__ __forceinline__ float bf2f(unsigned short b) {
    unsigned int u = ((unsigned int)b) << 16;
    return __builtin_bit_cast(float, u);
}

// ---- K0: BN-fold + build all bf16 hi/lo A-operands ----
__global__ void k0_prep(const float* __restrict__ w_qkv,
                        const float* __restrict__ w_out, const float* __restrict__ b_out,
                        const float* __restrict__ g_out, const float* __restrict__ be_out,
                        const float* __restrict__ m_out, const float* __restrict__ v_out,
                        const float* __restrict__ w_ff,  const float* __restrict__ b_ff,
                        const float* __restrict__ g_ff,  const float* __restrict__ be_ff,
                        const float* __restrict__ m_ff,  const float* __restrict__ v_ff,
                        const float* __restrict__ w_t,   const float* __restrict__ b_t,
                        const float* __restrict__ g_t,   const float* __restrict__ be_t,
                        const float* __restrict__ m_t,   const float* __restrict__ v_t,
                        const float* __restrict__ w_ress,const float* __restrict__ b_ress,
                        const float* __restrict__ g_ress,const float* __restrict__ be_ress,
                        const float* __restrict__ m_ress,const float* __restrict__ v_ress,
                        const float* __restrict__ w_rest,const float* __restrict__ b_rest,
                        const float* __restrict__ g_rest,const float* __restrict__ be_rest,
                        const float* __restrict__ m_rest,const float* __restrict__ v_rest,
                        float* __restrict__ ws)
{
    int tid = blockIdx.x * blockDim.x + threadIdx.x;
    int np = gridDim.x * blockDim.x;

    unsigned short* wqh = (unsigned short*)(ws + OFF_WQHI);
    unsigned short* wql = (unsigned short*)(ws + OFF_WQLO);
    for (int idx = tid; idx < 96 * 64; idx += np) {
        float val = w_qkv[idx];
        unsigned short hi = f2bf_rne(val);
        wqh[idx] = hi;
        wql[idx] = f2bf_rne(val - bf2f(hi));
    }

    unsigned short* w3h = (unsigned short*)(ws + OFF_WA3HI);
    unsigned short* w3l = (unsigned short*)(ws + OFF_WA3LO);
    for (int idx = tid; idx < 128 * 256; idx += np) {
        int o = idx >> 8, k = idx & 255;
        float val;
        if (k < 192) {
            float sc = g_out[o] * rsqrtf(v_out[o] + EPSF);
            val = w_out[o * 192 + k] * sc;
        } else {
            float sc = g_ress[o] * rsqrtf(v_ress[o] + EPSF);
            val = w_ress[o * 64 + (k - 192)] * sc;
        }
        unsigned short hi = f2bf_rne(val);
        w3h[idx] = hi;
        w3l[idx] = f2bf_rne(val - bf2f(hi));
    }

    unsigned short* w4h = (unsigned short*)(ws + OFF_WA4HI);
    unsigned short* w4l = (unsigned short*)(ws + OFF_WA4LO);
    for (int idx = tid; idx < 128 * 192; idx += np) {
        int o = idx / 192, k = idx % 192;
        float val;
        if (k < 128) {
            float sc = g_ff[o] * rsqrtf(v_ff[o] + EPSF);
            val = w_ff[o * 128 + k] * sc;
        } else {
            float sc = g_ress[o] * rsqrtf(v_ress[o] + EPSF);
            val = w_ress[o * 64 + (k - 128)] * sc;
        }
        unsigned short hi = f2bf_rne(val);
        w4h[idx] = hi;
        w4l[idx] = f2bf_rne(val - bf2f(hi));
    }

    unsigned short* w5h = (unsigned short*)(ws + OFF_WA5HI);
    unsigned short* w5l = (unsigned short*)(ws + OFF_WA5LO);
    for (int idx = tid; idx < 128 * 1024; idx += np) {
        int o = idx >> 10, kk = idx & 1023;
        int tap = kk >> 7, i = kk & 127;
        float val;
        if (tap < 7) {
            float sc = g_t[o] * rsqrtf(v_t[o] + EPSF);
            val = w_t[((size_t)o * 128 + i) * 7 + tap] * sc;
        } else {
            float sc = g_rest[o] * rsqrtf(v_rest[o] + EPSF);
            val = w_rest[o * 128 + i] * sc;
        }
        unsigned short hi = f2bf_rne(val);
        w5h[idx] = hi;
        w5l[idx] = f2bf_rne(val - bf2f(hi));
    }

    for (int o = tid; o < 128; o += np) {
        float sco = g_out[o] * rsqrtf(v_out[o] + EPSF);
        float scr = g_ress[o] * rsqrtf(v_ress[o] + EPSF);
        float scf = g_ff[o] * rsqrtf(v_ff[o] + EPSF);
        float sct = g_t[o] * rsqrtf(v_t[o] + EPSF);
        float sce = g_rest[o] * rsqrtf(v_rest[o] + EPSF);
        float bres = (b_ress[o] - m_ress[o]) * scr + be_ress[o];
        ws[OFF_B3 + o] = (b_out[o] - m_out[o]) * sco + be_out[o] + bres;
        ws[OFF_B4 + o] = (b_ff[o] - m_ff[o]) * scf + be_ff[o] + bres;
        ws[OFF_B5 + o] = (b_t[o] - m_t[o]) * sct + be_t[o]
                       + (b_rest[o] - m_rest[o]) * sce + be_rest[o];
    }
}

// ---- k_xt: x[n][c][t][v] -> xT[n][col][64] bf16 hi/lo ----
__global__ __launch_bounds__(256) void k_xt(const float* __restrict__ x,
                                            unsigned short* __restrict__ xthi,
                                            unsigned short* __restrict__ xtlo)
{
    __shared__ float Xs[64][26];
    int nt = blockIdx.x;
    int n = nt >> 7, t = nt & 127;
    const float* xb = x + ((size_t)n * C_ * T_ + t) * V_;
    for (int e = threadIdx.x; e < 1600; e += 256) {
        int c = e / 25, u = e % 25;
        Xs[c][u] = xb[(size_t)c * (T_ * V_) + u];
    }
    __syncthreads();
    unsigned short* dh = xthi + ((size_t)n * COLS + t * 25) * 64;
    unsigned short* dl = xtlo + ((size_t)n * COLS + t * 25) * 64;
    for (int e = threadIdx.x; e < 1600; e += 256) {
        int v = e >> 6, c = e & 63;
        float val = Xs[c][v];
        unsigned short hi = f2bf_rne(val);
        dh[(size_t)v * 64 + c] = hi;
        dl[(size_t)v * 64 + c] = f2bf_rne(val - bf2f(hi));
    }
}

// ---- k1: qkv GEMM M=96,K=64 -> qk bf16 [n][96][3200] ----
__global__ __launch_bounds__(256, 2) void k1_mfma(const unsigned short* __restrict__ wqh,
                                                   const unsigned short* __restrict__ wql,
                                                   const unsigned short* __restrict__ xthi,
                                                   const unsigned short* __restrict__ xtlo,
                                                   const float* __restrict__ b_qkv,
                                                   unsigned short* __restrict__ qk)
{
    __shared__ unsigned short Ah[96][40], Al[96][40], Bh[128][40], Bl[128][40];
    int blk = blockIdx.x;
    int n = blk / 25, ct = blk % 25;
    int c0 = ct * 128;
    int tid = threadIdx.x, lane = tid & 63, wid = tid >> 6;
    int wm = wid & 1, wn = wid >> 1;
    const unsigned short* xh = xthi + (size_t)n * COLS * 64;
    const unsigned short* xl = xtlo + (size_t)n * COLS * 64;
    f32x4 acc[3][4];
#pragma unroll
    for (int a = 0; a < 3; ++a)
#pragma unroll
        for (int b = 0; b < 4; ++b) acc[a][b] = (f32x4)0.f;
    int rbase = lane & 15, koff = (lane >> 4) * 8;

    for (int ks = 0; ks < 2; ++ks) {
        __syncthreads();
        for (int L = tid; L < 384; L += 256) {
            int o = L >> 2, g = (L & 3) * 8;
            *(ushort8*)&Ah[o][g] = *(const ushort8*)&wqh[(size_t)o * 64 + ks * 32 + g];
            *(ushort8*)&Al[o][g] = *(const ushort8*)&wql[(size_t)o * 64 + ks * 32 + g];
        }
        for (int L = tid; L < 512; L += 256) {
            int col = L >> 2, g = (L & 3) * 8;
            size_t src = (size_t)(c0 + col) * 64 + ks * 32 + g;
            *(ushort8*)&Bh[col][g] = *(const ushort8*)&xh[src];
            *(ushort8*)&Bl[col][g] = *(const ushort8*)&xl[src];
        }
        __syncthreads();
        short8 afh[3], afl[3], bfh[4], bfl[4];
#pragma unroll
        for (int mb = 0; mb < 3; ++mb) {
            int row = wm * 48 + mb * 16 + rbase;
            afh[mb] = *(const short8*)&Ah[row][koff];
            afl[mb] = *(const short8*)&Al[row][koff];
        }
#pragma unroll
        for (int nb = 0; nb < 4; ++nb) {
            int col = wn * 64 + nb * 16 + rbase;
            bfh[nb] = *(const short8*)&Bh[col][koff];
            bfl[nb] = *(const short8*)&Bl[col][koff];
        }
#pragma unroll
        for (int mb = 0; mb < 3; ++mb)
#pragma unroll
            for (int nb = 0; nb < 4; ++nb) {
                acc[mb][nb] = __builtin_amdgcn_mfma_f32_16x16x32_bf16(afh[mb], bfh[nb], acc[mb][nb], 0, 0, 0);
                acc[mb][nb] = __builtin_amdgcn_mfma_f32_16x16x32_bf16(afh[mb], bfl[nb], acc[mb][nb], 0, 0, 0);
                acc[mb][nb] = __builtin_amdgcn_mfma_f32_16x16x32_bf16(afl[mb], bfh[nb], acc[mb][nb], 0, 0, 0);
            }
    }
#pragma unroll
    for (int mb = 0; mb < 3; ++mb) {
#pragma unroll
        for (int nb = 0; nb < 4; ++nb) {
            int col = c0 + wn * 64 + nb * 16 + (lane & 15);
#pragma unroll
            for (int r = 0; r < 4; ++r) {
                int o = wm * 48 + mb * 16 + (lane >> 4) * 4 + r;
                qk[((size_t)n * 96 + o) * COLS + col] = f2bf_rne(acc[mb][nb][r] + b_qkv[o]);
            }
        }
    }
}

// ---- k2: partial attention logits (T split 4-way) -> part[p][nh][u][v] ----
__global__ __launch_bounds__(256) void k2_att(const unsigned short* __restrict__ qk,
                                              float* __restrict__ part)
{
    int blk = blockIdx.x;
    int nh = blk >> 2, p = blk & 3;
    int n = nh / H_, h = nh % H_;
    __shared__ float Qs[D_][8][26];
    __shared__ float Ks[D_][8][26];
    float acc[3] = {0.f, 0.f, 0.f};
    const unsigned short* qbase = qk + (size_t)(n * 96 + h * 16) * COLS;
    const unsigned short* kbase = qk + (size_t)(n * 96 + 48 + h * 16) * COLS;
    for (int tc = p * 32; tc < p * 32 + 32; tc += 8) {
        __syncthreads();
        for (int e = threadIdx.x; e < 16 * 8 * 25; e += 256) {
            int d = e / 200, r = e % 200;
            int tt = r / 25, u = r % 25;
            Qs[d][tt][u] = bf2f(qbase[(size_t)d * COLS + (tc + tt) * 25 + u]);
            Ks[d][tt][u] = bf2f(kbase[(size_t)d * COLS + (tc + tt) * 25 + u]);
        }
        __syncthreads();
#pragma unroll
        for (int q = 0; q < 3; ++q) {
            int e = threadIdx.x + q * 256;
            if (e < 625) {
                int u = e / 25, v = e % 25;
                float a = acc[q];
                for (int tt = 0; tt < 8; ++tt) {
#pragma unroll
                    for (int d = 0; d < 16; ++d)
                        a += Qs[d][tt][u] * Ks[d][tt][v];
                }
                acc[q] = a;
            }
        }
    }
    float* pb = part + ((size_t)p * 384 + nh) * 625;
#pragma unroll
    for (int q = 0; q < 3; ++q) {
        int e = threadIdx.x + q * 256;
        if (e < 625) pb[e] = acc[q];
    }
}

// ---- k2b: combine partials + softmax -> att[n,h,u,v] ----
__global__ __launch_bounds__(64) void k2b_smax(const float* __restrict__ part,
                                               const float* __restrict__ values,
                                               const float* __restrict__ att_bias,
                                               float* __restrict__ att)
{
    int nh = blockIdx.x;
    int h = nh % H_;
    if (threadIdx.x < 25) {
        int u = threadIdx.x;
        float scale = values[h] / 2048.0f;
        float bias = att_bias[h];
        float L[25];
        float m = -1e30f;
        for (int v = 0; v < 25; ++v) {
            size_t idx = (size_t)nh * 625 + u * 25 + v;
            float s = part[idx] + part[384 * 625 + idx] + part[2 * 384 * 625 + idx]
                    + part[3 * 384 * 625 + idx];
            L[v] = s * scale + bias;
            m = fmaxf(m, L[v]);
        }
        float ex[25];
        float s = 0.f;
        for (int v = 0; v < 25; ++v) { ex[v] = expf(L[v] - m); s += ex[v]; }
        float inv = 1.0f / s;
        float* ab = att + (size_t)nh * 625 + u * 25;
        for (int v = 0; v < 25; ++v) ab[v] = ex[v] * inv;
    }
}

// ---- k_tm: Tm[hc][t,v] = sum_u x[c][t,u]*att[h][u][v] -> TmT[n][col][192] hi/lo ----
__global__ __launch_bounds__(192) void k_tm(const float* __restrict__ x,
                                            const float* __restrict__ att,
                                            unsigned short* __restrict__ tmhi,
                                            unsigned short* __restrict__ tmlo)
{
    __shared__ float Xs[64][26];
    __shared__ float As[3][25][26];
    int nt = blockIdx.x;
    int n = nt >> 7, t = nt & 127;
    const float* xb = x + ((size_t)n * C_ * T_ + t) * V_;
    for (int e = threadIdx.x; e < 1600; e += 192) {
        int c = e / 25, u = e % 25;
        Xs[c][u] = xb[(size_t)c * (T_ * V_) + u];
    }
    const float* ab = att + (size_t)n * 3 * 625;
    for (int e = threadIdx.x; e < 1875; e += 192) {
        int h = e / 625, r = e % 625;
        As[h][r / 25][r % 25] = ab[e];
    }
    __syncthreads();
    int hc = threadIdx.x;            // 0..191
    int h = hc >> 6, c = hc & 63;
    float xr[25];
#pragma unroll
    for (int u = 0; u < 25; ++u) xr[u] = Xs[c][u];
    unsigned short* dh = tmhi + ((size_t)n * COLS + t * 25) * 192 + hc;
    unsigned short* dl = tmlo + ((size_t)n * COLS + t * 25) * 192 + hc;
#pragma unroll 5
    for (int v = 0; v < 25; ++v) {
        float a = 0.f;
#pragma unroll
        for (int u = 0; u < 25; ++u) a += xr[u] * As[h][u][v];
        unsigned short hi = f2bf_rne(a);
        dh[(size_t)v * 192] = hi;
        dl[(size_t)v * 192] = f2bf_rne(a - bf2f(hi));
    }
}

// ---- k3: x1 GEMM M=128,K=256 (192 Tm + 64 x) -> x1T hi/lo (in d_out) ----
__global__ __launch_bounds__(256, 2) void k3_mfma(const unsigned short* __restrict__ w3h,
                                                   const unsigned short* __restrict__ w3l,
                                                   const unsigned short* __restrict__ tmhi,
                                                   const unsigned short* __restrict__ tmlo,
                                                   const unsigned short* __restrict__ xthi,
                                                   const unsigned short* __restrict__ xtlo,
                                                   const float* __restrict__ b3,
                                                   unsigned short* __restrict__ x1hi,
                                                   unsigned short* __restrict__ x1lo)
{
    __shared__ unsigned short Ah[128][40], Al[128][40], Bh[128][40], Bl[128][40];
    int blk = blockIdx.x;
    int n = blk / 25, ct = blk % 25;
    int c0 = ct * 128;
    int tid = threadIdx.x, lane = tid & 63, wid = tid >> 6;
    int wm = wid & 1, wn = wid >> 1;
    const unsigned short* th = tmhi + (size_t)n * COLS * 192;
    const unsigned short* tl = tmlo + (size_t)n * COLS * 192;
    const unsigned short* xh = xthi + (size_t)n * COLS * 64;
    const unsigned short* xl = xtlo + (size_t)n * COLS * 64;
    f32x4 acc[4][4];
#pragma unroll
    for (int a = 0; a < 4; ++a)
#pragma unroll
        for (int b = 0; b < 4; ++b) acc[a][b] = (f32x4)0.f;
    int rbase = lane & 15, koff = (lane >> 4) * 8;

    for (int ks = 0; ks < 8; ++ks) {
        __syncthreads();
        for (int L = tid; L < 512; L += 256) {
            int o = L >> 2, g = (L & 3) * 8;
            *(ushort8*)&Ah[o][g] = *(const ushort8*)&w3h[(size_t)o * 256 + ks * 32 + g];
            *(ushort8*)&Al[o][g] = *(const ushort8*)&w3l[(size_t)o * 256 + ks * 32 + g];
        }
        for (int L = tid; L < 512; L += 256) {
            int col = L >> 2, g = (L & 3) * 8;
            ushort8 vh, vl;
            if (ks < 6) {
                size_t src = (size_t)(c0 + col) * 192 + ks * 32 + g;
                vh = *(const ushort8*)&th[src];
                vl = *(const ushort8*)&tl[src];
            } else {
                size_t src = (size_t)(c0 + col) * 64 + (ks - 6) * 32 + g;
                vh = *(const ushort8*)&xh[src];
                vl = *(const ushort8*)&xl[src];
            }
            *(ushort8*)&Bh[col][g] = vh;
            *(ushort8*)&Bl[col][g] = vl;
        }
        __syncthreads();
        short8 afh[4], afl[4], bfh[4], bfl[4];
#pragma unroll
        for (int mb = 0; mb < 4; ++mb) {
            int row = wm * 64 + mb * 16 + rbase;
            afh[mb] = *(const short8*)&Ah[row][koff];
            afl[mb] = *(const short8*)&Al[row][koff];
        }
#pragma unroll
        for (int nb = 0; nb < 4; ++nb) {
            int col = wn * 64 + nb * 16 + rbase;
            bfh[nb] = *(const short8*)&Bh[col][koff];
            bfl[nb] = *(const short8*)&Bl[col][koff];
        }
#pragma unroll
        for (int mb = 0; mb < 4; ++mb)
#pragma unroll
            for (int nb = 0; nb < 4; ++nb) {
                acc[mb][nb] = __builtin_amdgcn_mfma_f32_16x16x32_bf16(afh[mb], bfh[nb], acc[mb][nb], 0, 0, 0);
                acc[mb][nb] = __builtin_amdgcn_mfma_f32_16x16x32_bf16(afh[mb], bfl[nb], acc[mb][nb], 0, 0, 0);
                acc[mb][nb] = __builtin_amdgcn_mfma_f32_16x16x32_bf16(afl[mb], bfh[nb], acc[mb][nb], 0, 0, 0);
            }
    }
#pragma unroll
    for (int mb = 0; mb < 4; ++mb) {
#pragma unroll
        for (int nb = 0; nb < 4; ++nb) {
            int col = c0 + wn * 64 + nb * 16 + (lane & 15);
            int obase = wm * 64 + mb * 16 + (lane >> 4) * 4;
            us4v hv, lv;
#pragma unroll
            for (int r = 0; r < 4; ++r) {
                float y = lrelu(acc[mb][nb][r] + b3[obase + r]);
                unsigned short hi = f2bf_rne(y);
                hv[r] = hi;
                lv[r] = f2bf_rne(y - bf2f(hi));
            }
            size_t dst = ((size_t)n * COLS + col) * 128 + obase;
            *(us4v*)&x1hi[dst] = hv;
            *(us4v*)&x1lo[dst] = lv;
        }
    }
}

// ---- k4: x2 GEMM M=128,K=192 (128 x1 + 64 x) -> x2T hi/lo ----
__global__ __launch_bounds__(256, 2) void k4_mfma(const unsigned short* __restrict__ w4h,
                                                   const unsigned short* __restrict__ w4l,
                                                   const unsigned short* __restrict__ x1hi,
                                                   const unsigned short* __restrict__ x1lo,
                                                   const unsigned short* __restrict__ xthi,
                                                   const unsigned short* __restrict__ xtlo,
                                                   const float* __restrict__ b4,
                                                   unsigned short* __restrict__ x2hi,
                                                   unsigned short* __restrict__ x2lo)
{
    __shared__ unsigned short Ah[128][40], Al[128][40], Bh[128][40], Bl[128][40];
    int blk = blockIdx.x;
    int n = blk / 25, ct = blk % 25;
    int c0 = ct * 128;
    int tid = threadIdx.x, lane = tid & 63, wid = tid >> 6;
    int wm = wid & 1, wn = wid >> 1;
    const unsigned short* ph = x1hi + (size_t)n * COLS * 128;
    const unsigned short* pl = x1lo + (size_t)n * COLS * 128;
    const unsigned short* xh = xthi + (size_t)n * COLS * 64;
    const unsigned short* xl = xtlo + (size_t)n * COLS * 64;
    f32x4 acc[4][4];
#pragma unroll
    for (int a = 0; a < 4; ++a)
#pragma unroll
        for (int b = 0; b < 4; ++b) acc[a][b] = (f32x4)0.f;
    int rbase = lane & 15, koff = (lane >> 4) * 8;

    for (int ks = 0; ks < 6; ++ks) {
        __syncthreads();
        for (int L = tid; L < 512; L += 256) {
            int o = L >> 2, g = (L & 3) * 8;
            *(ushort8*)&Ah[o][g] = *(const ushort8*)&w4h[(size_t)o * 192 + ks * 32 + g];
            *(ushort8*)&Al[o][g] = *(const ushort8*)&w4l[(size_t)o * 192 + ks * 32 + g];
        }
        for (int L = tid; L < 512; L += 256) {
            int col = L >> 2, g = (L & 3) * 8;
            ushort8 vh, vl;
            if (ks < 4) {
                size_t src = (size_t)(c0 + col) * 128 + ks * 32 + g;
                vh = *(const ushort8*)&ph[src];
                vl = *(const ushort8*)&pl[src];
            } else {
                size_t src = (size_t)(c0 + col) * 64 + (ks - 4) * 32 + g;
                vh = *(const ushort8*)&xh[src];
                vl = *(const ushort8*)&xl[src];
            }
            *(ushort8*)&Bh[col][g] = vh;
            *(ushort8*)&Bl[col][g] = vl;
        }
        __syncthreads();
        short8 afh[4], afl[4], bfh[4], bfl[4];
#pragma unroll
        for (int mb = 0; mb < 4; ++mb) {
            int row = wm * 64 + mb * 16 + rbase;
            afh[mb] = *(const short8*)&Ah[row][koff];
            afl[mb] = *(const short8*)&Al[row][koff];
        }
#pragma unroll
        for (int nb = 0; nb < 4; ++nb) {
            int col = wn * 64 + nb * 16 + rbase;
            bfh[nb] = *(const short8*)&Bh[col][koff];
            bfl[nb] = *(const short8*)&Bl[col][koff];
        }
#pragma unroll
        for (int mb = 0; mb < 4; ++mb)
#pragma unroll
            for (int nb = 0; nb < 4; ++nb) {
                acc[mb][nb] = __builtin_amdgcn_mfma_f32_16x16x32_bf16(afh[mb], bfh[nb], acc[mb][nb], 0, 0, 0);
                acc[mb][nb] = __builtin_amdgcn_mfma_f32_16x16x32_bf16(afh[mb], bfl[nb], acc[mb][nb], 0, 0, 0);
                acc[mb][nb] = __builtin_amdgcn_mfma_f32_16x16x32_bf16(afl[mb], bfh[nb], acc[mb][nb], 0, 0, 0);
            }
    }
#pragma unroll
    for (int mb = 0; mb < 4; ++mb) {
#pragma unroll
        for (int nb = 0; nb < 4; ++nb) {
            int col = c0 + wn * 64 + nb * 16 + (lane & 15);
            int obase = wm * 64 + mb * 16 + (lane >> 4) * 4;
            us4v hv, lv;
#pragma unroll
            for (int r = 0; r < 4; ++r) {
                float y = lrelu(acc[mb][nb][r] + b4[obase + r]);
                unsigned short hi = f2bf_rne(y);
                hv[r] = hi;
                lv[r] = f2bf_rne(y - bf2f(hi));
            }
            size_t dst = ((size_t)n * COLS + col) * 128 + obase;
            *(us4v*)&x2hi[dst] = hv;
            *(us4v*)&x2lo[dst] = lv;
        }
    }
}

// ---- k5: fused temporal(K=7)+rest conv GEMM M=128,K=1024 -> out fp32 ----
// i-chunk-major: stage wide B tile (cols c0-75..c0+202, 32 i) once, reuse for all 8 taps.
__global__ __launch_bounds__(256, 2) void k5_mfma(const unsigned short* __restrict__ wAhi,
                                                  const unsigned short* __restrict__ wAlo,
                                                  const unsigned short* __restrict__ x2hiT,
                                                  const unsigned short* __restrict__ x2loT,
                                                  const float* __restrict__ bcomb,
                                                  float* __restrict__ out)
{
    __shared__ unsigned short Ah[128][40];
    __shared__ unsigned short Al[128][40];
    __shared__ unsigned short Bh[280][40];
    __shared__ unsigned short Bl[280][40];

    int blk = blockIdx.x;
    int n = blk / 25, ct = blk % 25;
    int c0 = ct * 128;
    int tid = threadIdx.x;
    int lane = tid & 63, wid = tid >> 6;
    int wm = wid & 1, wn = wid >> 1;

    const unsigned short* x2h_n = x2hiT + (size_t)n * 409600;
    const unsigned short* x2l_n = x2loT + (size_t)n * 409600;

    f32x4 acc[4][4];
#pragma unroll
    for (int a = 0; a < 4; ++a)
#pragma unroll
        for (int b = 0; b < 4; ++b) acc[a][b] = (f32x4)0.f;

    int rbase = lane & 15;
    int koff = (lane >> 4) * 8;
    int base = c0 - 75;

    for (int ic = 0; ic < 4; ++ic) {
        int i0 = ic * 32;
        __syncthreads();
        // stage wide B: 278 cols x 32 i, both planes (each element read from HBM exactly once)
        for (int L = tid; L < 1112; L += 256) {
            int w = L >> 2, g = (L & 3) * 8;
            int cs = base + w;
            ushort8 vh = (ushort8)0, vl = (ushort8)0;
            if (cs >= 0 && cs < 3200) {
                vh = *(const ushort8*)&x2h_n[(size_t)cs * 128 + i0 + g];
                vl = *(const ushort8*)&x2l_n[(size_t)cs * 128 + i0 + g];
            }
            *(ushort8*)&Bh[w][g] = vh;
            *(ushort8*)&Bl[w][g] = vl;
        }
        for (int tap = 0; tap < 8; ++tap) {
            if (tap) __syncthreads();
            int kk0 = tap * 128 + i0;
            for (int L = tid; L < 512; L += 256) {
                int o = L >> 2, g = (L & 3) * 8;
                *(ushort8*)&Ah[o][g] = *(const ushort8*)&wAhi[(size_t)o * 1024 + kk0 + g];
                *(ushort8*)&Al[o][g] = *(const ushort8*)&wAlo[(size_t)o * 1024 + kk0 + g];
            }
            __syncthreads();
            int wofs = (tap < 7) ? (75 + 25 * (tap - 3)) : 75;
            short8 afh[4], afl[4], bfh[4], bfl[4];
#pragma unroll
            for (int mb = 0; mb < 4; ++mb) {
                int row = wm * 64 + mb * 16 + rbase;
                afh[mb] = *(const short8*)&Ah[row][koff];
                afl[mb] = *(const short8*)&Al[row][koff];
            }
#pragma unroll
            for (int nb = 0; nb < 4; ++nb) {
                int w = wn * 64 + nb * 16 + rbase + wofs;
                bfh[nb] = *(const short8*)&Bh[w][koff];
                bfl[nb] = *(const short8*)&Bl[w][koff];
            }
#pragma unroll
            for (int mb = 0; mb < 4; ++mb)
#pragma unroll
                for (int nb = 0; nb < 4; ++nb) {
                    acc[mb][nb] = __builtin_amdgcn_mfma_f32_16x16x32_bf16(afh[mb], bfh[nb], acc[mb][nb], 0, 0, 0);
                    acc[mb][nb] = __builtin_amdgcn_mfma_f32_16x16x32_bf16(afh[mb], bfl[nb], acc[mb][nb], 0, 0, 0);
                    acc[mb][nb] = __builtin_amdgcn_mfma_f32_16x16x32_bf16(afl[mb], bfh[nb], acc[mb][nb], 0, 0, 0);
                }
        }
    }
#pragma unroll
    for (int mb = 0; mb < 4; ++mb) {
#pragma unroll
        for (int nb = 0; nb < 4; ++nb) {
            int col = c0 + wn * 64 + nb * 16 + (lane & 15);
#pragma unroll
            for (int r = 0; r < 4; ++r) {
                int o = wm * 64 + mb * 16 + (lane >> 4) * 4 + r;
                float y = acc[mb][nb][r] + bcomb[o];
                out[((size_t)n * 128 + o) * 3200 + col] = lrelu(y);
            }
        }
    }
}

extern "C" void kernel_launch(void* const* d_in, const int* in_sizes, int n_in,
                              void* d_out, int out_size, void* d_ws, size_t ws_size,
                              hipStream_t stream)
{
    const float* x       = (const float*)d_in[0];
    const float* w_qkv   = (const float*)d_in[1];
    const float* b_qkv   = (const float*)d_in[2];
    const float* values  = (const float*)d_in[3];
    const float* att_bias= (const float*)d_in[4];
    const float* w_out   = (const float*)d_in[5];
    const float* b_out   = (const float*)d_in[6];
    const float* g_out   = (const float*)d_in[7];
    const float* be_out  = (const float*)d_in[8];
    const float* m_out   = (const float*)d_in[9];
    const float* v_out   = (const float*)d_in[10];
    const float* w_ff    = (const float*)d_in[11];
    const float* b_ff    = (const float*)d_in[12];
    const float* g_ff    = (const float*)d_in[13];
    const float* be_ff   = (const float*)d_in[14];
    const float* m_ff    = (const float*)d_in[15];
    const float* v_ff    = (const float*)d_in[16];
    const float* w_t     = (const float*)d_in[17];
    const float* b_t     = (const float*)d_in[18];
    const float* g_t     = (const float*)d_in[19];
    const float* be_t    = (const float*)d_in[20];
    const float* m_t     = (const float*)d_in[21];
    const float* v_t     = (const float*)d_in[22];
    const float* w_ress  = (const float*)d_in[23];
    const float* b_ress  = (const float*)d_in[24];
    const float* g_ress  = (const float*)d_in[25];
    const float* be_ress = (const float*)d_in[26];
    const float* m_ress  = (const float*)d_in[27];
    const float* v_ress  = (const float*)d_in[28];
    const float* w_rest  = (const float*)d_in[29];
    const float* b_rest  = (const float*)d_in[30];
    const float* g_rest  = (const float*)d_in[31];
    const float* be_rest = (const float*)d_in[32];
    const float* m_rest  = (const float*)d_in[33];
    const float* v_rest  = (const float*)d_in[34];

    float* ws = (float*)d_ws;
    float* out = (float*)d_out;

    unsigned short* xthi = (unsigned short*)(ws + OFF_XTHI);
    unsigned short* xtlo = (unsigned short*)(ws + OFF_XTLO);
    unsigned short* qk   = (unsigned short*)(ws + OFF_BIG);
    float*          part = ws + OFF_PART;
    unsigned short* tmhi = (unsigned short*)(ws + OFF_BIG);
    unsigned short* tmlo = (unsigned short*)(ws + OFF_BIG + 39321600);
    unsigned short* x2hi = (unsigned short*)(ws + OFF_BIG);
    unsigned short* x2lo = (unsigned short*)(ws + OFF_BIG + 26214400);
    unsigned short* x1hi = (unsigned short*)out;
    unsigned short* x1lo = x1hi + 52428800;

    k0_prep<<<128, 256, 0, stream>>>(w_qkv,
        w_out, b_out, g_out, be_out, m_out, v_out,
        w_ff, b_ff, g_ff, be_ff, m_ff, v_ff,
        w_t, b_t, g_t, be_t, m_t, v_t,
        w_ress, b_ress, g_ress, be_ress, m_ress, v_ress,
        w_rest, b_rest, g_rest, be_rest, m_rest, v_rest,
        ws);
    k_xt<<<N_ * T_, 256, 0, stream>>>(x, xthi, xtlo);
    k1_mfma<<<N_ * 25, 256, 0, stream>>>(
        (const unsigned short*)(ws + OFF_WQHI), (const unsigned short*)(ws + OFF_WQLO),
        xthi, xtlo, b_qkv, qk);
    k2_att<<<N_ * H_ * 4, 256, 0, stream>>>(qk, part);
    k2b_smax<<<N_ * H_, 64, 0, stream>>>(part, values, att_bias, ws + OFF_ATT);
    k_tm<<<N_ * T_, 192, 0, stream>>>(x, ws + OFF_ATT, tmhi, tmlo);
    k3_mfma<<<N_ * 25, 256, 0, stream>>>(
        (const unsigned short*)(ws + OFF_WA3HI), (const unsigned short*)(ws + OFF_WA3LO),
        tmhi, tmlo, xthi, xtlo, ws + OFF_B3, x1hi, x1lo);
    k4_mfma<<<N_ * 25, 256, 0, stream>>>(
        (const unsigned short*)(ws + OFF_WA4HI), (const unsigned short*)(ws + OFF_WA4LO),
        x1hi, x1lo, xthi, xtlo, ws + OFF_B4, x2hi, x2lo);
    k5_mfma<<<N_ * 25, 256, 0, stream>>>(
        (const unsigned short*)(ws + OFF_WA5HI), (const unsigned short*)(ws + OFF_WA5LO),
        x2hi, x2lo, ws + OFF_B5, out);
}

// Round 8
// 803.183 us; speedup vs baseline: 8.2441x; 1.5769x over previous
//
#include <hip/hip_runtime.h>

#define N_  128
#define C_  64
#define T_  128
#define V_  25
#define CO_ 128
#define H_  3
#define D_  16

constexpr int COLS = 3200;
constexpr float EPSF = 1e-5f;

typedef __attribute__((ext_vector_type(8))) short short8;
typedef __attribute__((ext_vector_type(8))) unsigned short ushort8;
typedef __attribute__((ext_vector_type(4))) unsigned short us4v;
typedef __attribute__((ext_vector_type(4))) float f32x4;

// ---- workspace layout (float units) ----
constexpr size_t OFF_ATT  = 0;                          // 240,000
constexpr size_t OFF_XTHI = 240000;                     // 13,107,200 fl (26.2M ushorts)
constexpr size_t OFF_BIG  = OFF_XTHI + 13107200;        // time-shared:
//   phase A: qk bf16 [n][96][3200] (19.7M fl) ; part at +20M fl
//   phase B: TmT bf16 [n][3200][192] (39.3M fl)
//   phase C: x2T bf16 [n][3200][128] (26.2M fl)
constexpr size_t BIGF     = 78643200;
constexpr size_t OFF_PART = OFF_BIG + 20000000;         // 960,000 floats (4*384*625)
constexpr size_t OFF_W    = OFF_BIG + BIGF;
constexpr size_t OFF_WQHI  = OFF_W;                     // 96*64 us = 3072 fl
constexpr size_t OFF_WA3HI = OFF_WQHI + 3072;           // 128*256 us = 16384 fl
constexpr size_t OFF_WA4HI = OFF_WA3HI + 16384;         // 128*192 us = 12288 fl
constexpr size_t OFF_WA5HI = OFF_WA4HI + 12288;         // 128*1024 us = 65536 fl
constexpr size_t OFF_B3    = OFF_WA5HI + 65536;
constexpr size_t OFF_B4    = OFF_B3 + 128;
constexpr size_t OFF_B5    = OFF_B4 + 128;

__device__ __forceinline__ float lrelu(float y) { return y >= 0.f ? y : 0.1f * y; }

__device__ __forceinline__ unsigned short f2bf_rne(float f) {
    unsigned int u = __builtin_bit_cast(unsigned int, f);
    u += 0x7FFFu + ((u >> 16) & 1u);
    return (unsigned short)(u >> 16);
}
__device__ __forceinline__ float bf2f(unsigned short b) {
    unsigned int u = ((unsigned int)b) << 16;
    return __builtin_bit_cast(float, u);
}

// ---- K0: BN-fold + bf16 A-operands (single plane) ----
__global__ void k0_prep(const float* __restrict__ w_qkv,
                        const float* __restrict__ w_out, const float* __restrict__ b_out,
                        const float* __restrict__ g_out, const float* __restrict__ be_out,
                        const float* __restrict__ m_out, const float* __restrict__ v_out,
                        const float* __restrict__ w_ff,  const float* __restrict__ b_ff,
                        const float* __restrict__ g_ff,  const float* __restrict__ be_ff,
                        const float* __restrict__ m_ff,  const float* __restrict__ v_ff,
                        const float* __restrict__ w_t,   const float* __restrict__ b_t,
                        const float* __restrict__ g_t,   const float* __restrict__ be_t,
                        const float* __restrict__ m_t,   const float* __restrict__ v_t,
                        const float* __restrict__ w_ress,const float* __restrict__ b_ress,
                        const float* __restrict__ g_ress,const float* __restrict__ be_ress,
                        const float* __restrict__ m_ress,const float* __restrict__ v_ress,
                        const float* __restrict__ w_rest,const float* __restrict__ b_rest,
                        const float* __restrict__ g_rest,const float* __restrict__ be_rest,
                        const float* __restrict__ m_rest,const float* __restrict__ v_rest,
                        float* __restrict__ ws)
{
    int tid = blockIdx.x * blockDim.x + threadIdx.x;
    int np = gridDim.x * blockDim.x;

    unsigned short* wqh = (unsigned short*)(ws + OFF_WQHI);
    for (int idx = tid; idx < 96 * 64; idx += np)
        wqh[idx] = f2bf_rne(w_qkv[idx]);

    unsigned short* w3h = (unsigned short*)(ws + OFF_WA3HI);
    for (int idx = tid; idx < 128 * 256; idx += np) {
        int o = idx >> 8, k = idx & 255;
        float val;
        if (k < 192) {
            float sc = g_out[o] * rsqrtf(v_out[o] + EPSF);
            val = w_out[o * 192 + k] * sc;
        } else {
            float sc = g_ress[o] * rsqrtf(v_ress[o] + EPSF);
            val = w_ress[o * 64 + (k - 192)] * sc;
        }
        w3h[idx] = f2bf_rne(val);
    }

    unsigned short* w4h = (unsigned short*)(ws + OFF_WA4HI);
    for (int idx = tid; idx < 128 * 192; idx += np) {
        int o = idx / 192, k = idx % 192;
        float val;
        if (k < 128) {
            float sc = g_ff[o] * rsqrtf(v_ff[o] + EPSF);
            val = w_ff[o * 128 + k] * sc;
        } else {
            float sc = g_ress[o] * rsqrtf(v_ress[o] + EPSF);
            val = w_ress[o * 64 + (k - 128)] * sc;
        }
        w4h[idx] = f2bf_rne(val);
    }

    unsigned short* w5h = (unsigned short*)(ws + OFF_WA5HI);
    for (int idx = tid; idx < 128 * 1024; idx += np) {
        int o = idx >> 10, kk = idx & 1023;
        int tap = kk >> 7, i = kk & 127;
        float val;
        if (tap < 7) {
            float sc = g_t[o] * rsqrtf(v_t[o] + EPSF);
            val = w_t[((size_t)o * 128 + i) * 7 + tap] * sc;
        } else {
            float sc = g_rest[o] * rsqrtf(v_rest[o] + EPSF);
            val = w_rest[o * 128 + i] * sc;
        }
        w5h[idx] = f2bf_rne(val);
    }

    for (int o = tid; o < 128; o += np) {
        float sco = g_out[o] * rsqrtf(v_out[o] + EPSF);
        float scr = g_ress[o] * rsqrtf(v_ress[o] + EPSF);
        float scf = g_ff[o] * rsqrtf(v_ff[o] + EPSF);
        float sct = g_t[o] * rsqrtf(v_t[o] + EPSF);
        float sce = g_rest[o] * rsqrtf(v_rest[o] + EPSF);
        float bres = (b_ress[o] - m_ress[o]) * scr + be_ress[o];
        ws[OFF_B3 + o] = (b_out[o] - m_out[o]) * sco + be_out[o] + bres;
        ws[OFF_B4 + o] = (b_ff[o] - m_ff[o]) * scf + be_ff[o] + bres;
        ws[OFF_B5 + o] = (b_t[o] - m_t[o]) * sct + be_t[o]
                       + (b_rest[o] - m_rest[o]) * sce + be_rest[o];
    }
}

// ---- k_xt: x[n][c][t][v] -> xT[n][col][64] bf16 ----
__global__ __launch_bounds__(256) void k_xt(const float* __restrict__ x,
                                            unsigned short* __restrict__ xthi)
{
    __shared__ float Xs[64][26];
    int nt = blockIdx.x;
    int n = nt >> 7, t = nt & 127;
    const float* xb = x + ((size_t)n * C_ * T_ + t) * V_;
    for (int e = threadIdx.x; e < 1600; e += 256) {
        int c = e / 25, u = e % 25;
        Xs[c][u] = xb[(size_t)c * (T_ * V_) + u];
    }
    __syncthreads();
    unsigned short* dh = xthi + ((size_t)n * COLS + t * 25) * 64;
    for (int e = threadIdx.x; e < 1600; e += 256) {
        int v = e >> 6, c = e & 63;
        dh[(size_t)v * 64 + c] = f2bf_rne(Xs[c][v]);
    }
}

// ---- k1: qkv GEMM M=96,K=64 -> qk bf16 [n][96][3200] ----
__global__ __launch_bounds__(256, 2) void k1_mfma(const unsigned short* __restrict__ wqh,
                                                   const unsigned short* __restrict__ xthi,
                                                   const float* __restrict__ b_qkv,
                                                   unsigned short* __restrict__ qk)
{
    __shared__ unsigned short Ah[96][40], Bh[128][40];
    int blk = blockIdx.x;
    int n = blk / 25, ct = blk % 25;
    int c0 = ct * 128;
    int tid = threadIdx.x, lane = tid & 63, wid = tid >> 6;
    int wm = wid & 1, wn = wid >> 1;
    const unsigned short* xh = xthi + (size_t)n * COLS * 64;
    f32x4 acc[3][4];
#pragma unroll
    for (int a = 0; a < 3; ++a)
#pragma unroll
        for (int b = 0; b < 4; ++b) acc[a][b] = (f32x4)0.f;
    int rbase = lane & 15, koff = (lane >> 4) * 8;

    for (int ks = 0; ks < 2; ++ks) {
        __syncthreads();
        for (int L = tid; L < 384; L += 256) {
            int o = L >> 2, g = (L & 3) * 8;
            *(ushort8*)&Ah[o][g] = *(const ushort8*)&wqh[(size_t)o * 64 + ks * 32 + g];
        }
        for (int L = tid; L < 512; L += 256) {
            int col = L >> 2, g = (L & 3) * 8;
            size_t src = (size_t)(c0 + col) * 64 + ks * 32 + g;
            *(ushort8*)&Bh[col][g] = *(const ushort8*)&xh[src];
        }
        __syncthreads();
        short8 afh[3], bfh[4];
#pragma unroll
        for (int mb = 0; mb < 3; ++mb)
            afh[mb] = *(const short8*)&Ah[wm * 48 + mb * 16 + rbase][koff];
#pragma unroll
        for (int nb = 0; nb < 4; ++nb)
            bfh[nb] = *(const short8*)&Bh[wn * 64 + nb * 16 + rbase][koff];
#pragma unroll
        for (int mb = 0; mb < 3; ++mb)
#pragma unroll
            for (int nb = 0; nb < 4; ++nb)
                acc[mb][nb] = __builtin_amdgcn_mfma_f32_16x16x32_bf16(afh[mb], bfh[nb], acc[mb][nb], 0, 0, 0);
    }
#pragma unroll
    for (int mb = 0; mb < 3; ++mb) {
#pragma unroll
        for (int nb = 0; nb < 4; ++nb) {
            int col = c0 + wn * 64 + nb * 16 + (lane & 15);
#pragma unroll
            for (int r = 0; r < 4; ++r) {
                int o = wm * 48 + mb * 16 + (lane >> 4) * 4 + r;
                qk[((size_t)n * 96 + o) * COLS + col] = f2bf_rne(acc[mb][nb][r] + b_qkv[o]);
            }
        }
    }
}

// ---- k2: partial attention logits (T split 4-way) -> part[p][nh][u][v] ----
__global__ __launch_bounds__(256) void k2_att(const unsigned short* __restrict__ qk,
                                              float* __restrict__ part)
{
    int blk = blockIdx.x;
    int nh = blk >> 2, p = blk & 3;
    int n = nh / H_, h = nh % H_;
    __shared__ float Qs[D_][8][26];
    __shared__ float Ks[D_][8][26];
    float acc[3] = {0.f, 0.f, 0.f};
    const unsigned short* qbase = qk + (size_t)(n * 96 + h * 16) * COLS;
    const unsigned short* kbase = qk + (size_t)(n * 96 + 48 + h * 16) * COLS;
    for (int tc = p * 32; tc < p * 32 + 32; tc += 8) {
        __syncthreads();
        for (int e = threadIdx.x; e < 16 * 8 * 25; e += 256) {
            int d = e / 200, r = e % 200;
            int tt = r / 25, u = r % 25;
            Qs[d][tt][u] = bf2f(qbase[(size_t)d * COLS + (tc + tt) * 25 + u]);
            Ks[d][tt][u] = bf2f(kbase[(size_t)d * COLS + (tc + tt) * 25 + u]);
        }
        __syncthreads();
#pragma unroll
        for (int q = 0; q < 3; ++q) {
            int e = threadIdx.x + q * 256;
            if (e < 625) {
                int u = e / 25, v = e % 25;
                float a = acc[q];
                for (int tt = 0; tt < 8; ++tt) {
#pragma unroll
                    for (int d = 0; d < 16; ++d)
                        a += Qs[d][tt][u] * Ks[d][tt][v];
                }
                acc[q] = a;
            }
        }
    }
    float* pb = part + ((size_t)p * 384 + nh) * 625;
#pragma unroll
    for (int q = 0; q < 3; ++q) {
        int e = threadIdx.x + q * 256;
        if (e < 625) pb[e] = acc[q];
    }
}

// ---- k2b: combine partials + softmax -> att[n,h,u,v] ----
__global__ __launch_bounds__(64) void k2b_smax(const float* __restrict__ part,
                                               const float* __restrict__ values,
                                               const float* __restrict__ att_bias,
                                               float* __restrict__ att)
{
    int nh = blockIdx.x;
    int h = nh % H_;
    if (threadIdx.x < 25) {
        int u = threadIdx.x;
        float scale = values[h] / 2048.0f;
        float bias = att_bias[h];
        float L[25];
        float m = -1e30f;
        for (int v = 0; v < 25; ++v) {
            size_t idx = (size_t)nh * 625 + u * 25 + v;
            float s = part[idx] + part[384 * 625 + idx] + part[2 * 384 * 625 + idx]
                    + part[3 * 384 * 625 + idx];
            L[v] = s * scale + bias;
            m = fmaxf(m, L[v]);
        }
        float ex[25];
        float s = 0.f;
        for (int v = 0; v < 25; ++v) { ex[v] = expf(L[v] - m); s += ex[v]; }
        float inv = 1.0f / s;
        float* ab = att + (size_t)nh * 625 + u * 25;
        for (int v = 0; v < 25; ++v) ab[v] = ex[v] * inv;
    }
}

// ---- k_tm: Tm[hc][t,v] = sum_u x[c][t,u]*att[h][u][v] -> TmT[n][col][192] bf16 ----
__global__ __launch_bounds__(192) void k_tm(const float* __restrict__ x,
                                            const float* __restrict__ att,
                                            unsigned short* __restrict__ tmhi)
{
    __shared__ float Xs[64][26];
    __shared__ float As[3][25][26];
    int nt = blockIdx.x;
    int n = nt >> 7, t = nt & 127;
    const float* xb = x + ((size_t)n * C_ * T_ + t) * V_;
    for (int e = threadIdx.x; e < 1600; e += 192) {
        int c = e / 25, u = e % 25;
        Xs[c][u] = xb[(size_t)c * (T_ * V_) + u];
    }
    const float* ab = att + (size_t)n * 3 * 625;
    for (int e = threadIdx.x; e < 1875; e += 192) {
        int h = e / 625, r = e % 625;
        As[h][r / 25][r % 25] = ab[e];
    }
    __syncthreads();
    int hc = threadIdx.x;
    int h = hc >> 6, c = hc & 63;
    float xr[25];
#pragma unroll
    for (int u = 0; u < 25; ++u) xr[u] = Xs[c][u];
    unsigned short* dh = tmhi + ((size_t)n * COLS + t * 25) * 192 + hc;
#pragma unroll 5
    for (int v = 0; v < 25; ++v) {
        float a = 0.f;
#pragma unroll
        for (int u = 0; u < 25; ++u) a += xr[u] * As[h][u][v];
        dh[(size_t)v * 192] = f2bf_rne(a);
    }
}

// ---- k3: x1 GEMM M=128,K=256 (192 Tm + 64 x) -> x1T bf16 (in d_out) ----
__global__ __launch_bounds__(256, 2) void k3_mfma(const unsigned short* __restrict__ w3h,
                                                   const unsigned short* __restrict__ tmhi,
                                                   const unsigned short* __restrict__ xthi,
                                                   const float* __restrict__ b3,
                                                   unsigned short* __restrict__ x1hi)
{
    __shared__ unsigned short Ah[128][40], Bh[128][40];
    int blk = blockIdx.x;
    int n = blk / 25, ct = blk % 25;
    int c0 = ct * 128;
    int tid = threadIdx.x, lane = tid & 63, wid = tid >> 6;
    int wm = wid & 1, wn = wid >> 1;
    const unsigned short* th = tmhi + (size_t)n * COLS * 192;
    const unsigned short* xh = xthi + (size_t)n * COLS * 64;
    f32x4 acc[4][4];
#pragma unroll
    for (int a = 0; a < 4; ++a)
#pragma unroll
        for (int b = 0; b < 4; ++b) acc[a][b] = (f32x4)0.f;
    int rbase = lane & 15, koff = (lane >> 4) * 8;

    for (int ks = 0; ks < 8; ++ks) {
        __syncthreads();
        for (int L = tid; L < 512; L += 256) {
            int o = L >> 2, g = (L & 3) * 8;
            *(ushort8*)&Ah[o][g] = *(const ushort8*)&w3h[(size_t)o * 256 + ks * 32 + g];
        }
        for (int L = tid; L < 512; L += 256) {
            int col = L >> 2, g = (L & 3) * 8;
            ushort8 vh;
            if (ks < 6) {
                vh = *(const ushort8*)&th[(size_t)(c0 + col) * 192 + ks * 32 + g];
            } else {
                vh = *(const ushort8*)&xh[(size_t)(c0 + col) * 64 + (ks - 6) * 32 + g];
            }
            *(ushort8*)&Bh[col][g] = vh;
        }
        __syncthreads();
        short8 afh[4], bfh[4];
#pragma unroll
        for (int mb = 0; mb < 4; ++mb)
            afh[mb] = *(const short8*)&Ah[wm * 64 + mb * 16 + rbase][koff];
#pragma unroll
        for (int nb = 0; nb < 4; ++nb)
            bfh[nb] = *(const short8*)&Bh[wn * 64 + nb * 16 + rbase][koff];
#pragma unroll
        for (int mb = 0; mb < 4; ++mb)
#pragma unroll
            for (int nb = 0; nb < 4; ++nb)
                acc[mb][nb] = __builtin_amdgcn_mfma_f32_16x16x32_bf16(afh[mb], bfh[nb], acc[mb][nb], 0, 0, 0);
    }
#pragma unroll
    for (int mb = 0; mb < 4; ++mb) {
#pragma unroll
        for (int nb = 0; nb < 4; ++nb) {
            int col = c0 + wn * 64 + nb * 16 + (lane & 15);
            int obase = wm * 64 + mb * 16 + (lane >> 4) * 4;
            us4v hv;
#pragma unroll
            for (int r = 0; r < 4; ++r)
                hv[r] = f2bf_rne(lrelu(acc[mb][nb][r] + b3[obase + r]));
            *(us4v*)&x1hi[((size_t)n * COLS + col) * 128 + obase] = hv;
        }
    }
}

// ---- k4: x2 GEMM M=128,K=192 (128 x1 + 64 x) -> x2T bf16 ----
__global__ __launch_bounds__(256, 2) void k4_mfma(const unsigned short* __restrict__ w4h,
                                                   const unsigned short* __restrict__ x1hi,
                                                   const unsigned short* __restrict__ xthi,
                                                   const float* __restrict__ b4,
                                                   unsigned short* __restrict__ x2hi)
{
    __shared__ unsigned short Ah[128][40], Bh[128][40];
    int blk = blockIdx.x;
    int n = blk / 25, ct = blk % 25;
    int c0 = ct * 128;
    int tid = threadIdx.x, lane = tid & 63, wid = tid >> 6;
    int wm = wid & 1, wn = wid >> 1;
    const unsigned short* ph = x1hi + (size_t)n * COLS * 128;
    const unsigned short* xh = xthi + (size_t)n * COLS * 64;
    f32x4 acc[4][4];
#pragma unroll
    for (int a = 0; a < 4; ++a)
#pragma unroll
        for (int b = 0; b < 4; ++b) acc[a][b] = (f32x4)0.f;
    int rbase = lane & 15, koff = (lane >> 4) * 8;

    for (int ks = 0; ks < 6; ++ks) {
        __syncthreads();
        for (int L = tid; L < 512; L += 256) {
            int o = L >> 2, g = (L & 3) * 8;
            *(ushort8*)&Ah[o][g] = *(const ushort8*)&w4h[(size_t)o * 192 + ks * 32 + g];
        }
        for (int L = tid; L < 512; L += 256) {
            int col = L >> 2, g = (L & 3) * 8;
            ushort8 vh;
            if (ks < 4) {
                vh = *(const ushort8*)&ph[(size_t)(c0 + col) * 128 + ks * 32 + g];
            } else {
                vh = *(const ushort8*)&xh[(size_t)(c0 + col) * 64 + (ks - 4) * 32 + g];
            }
            *(ushort8*)&Bh[col][g] = vh;
        }
        __syncthreads();
        short8 afh[4], bfh[4];
#pragma unroll
        for (int mb = 0; mb < 4; ++mb)
            afh[mb] = *(const short8*)&Ah[wm * 64 + mb * 16 + rbase][koff];
#pragma unroll
        for (int nb = 0; nb < 4; ++nb)
            bfh[nb] = *(const short8*)&Bh[wn * 64 + nb * 16 + rbase][koff];
#pragma unroll
        for (int mb = 0; mb < 4; ++mb)
#pragma unroll
            for (int nb = 0; nb < 4; ++nb)
                acc[mb][nb] = __builtin_amdgcn_mfma_f32_16x16x32_bf16(afh[mb], bfh[nb], acc[mb][nb], 0, 0, 0);
    }
#pragma unroll
    for (int mb = 0; mb < 4; ++mb) {
#pragma unroll
        for (int nb = 0; nb < 4; ++nb) {
            int col = c0 + wn * 64 + nb * 16 + (lane & 15);
            int obase = wm * 64 + mb * 16 + (lane >> 4) * 4;
            us4v hv;
#pragma unroll
            for (int r = 0; r < 4; ++r)
                hv[r] = f2bf_rne(lrelu(acc[mb][nb][r] + b4[obase + r]));
            *(us4v*)&x2hi[((size_t)n * COLS + col) * 128 + obase] = hv;
        }
    }
}

// ---- k5: fused temporal(K=7)+rest conv. B wide-tile in LDS (once per i-chunk),
//      A-fragments from global (L2-resident) with one-tap-ahead register prefetch.
__global__ __launch_bounds__(256, 2) void k5_mfma(const unsigned short* __restrict__ wAhi,
                                                  const unsigned short* __restrict__ x2hiT,
                                                  const float* __restrict__ bcomb,
                                                  float* __restrict__ out)
{
    __shared__ unsigned short Bh[280][40];

    int blk = blockIdx.x;
    int n = blk / 25, ct = blk % 25;
    int c0 = ct * 128;
    int tid = threadIdx.x;
    int lane = tid & 63, wid = tid >> 6;
    int wm = wid & 1, wn = wid >> 1;

    const unsigned short* x2h_n = x2hiT + (size_t)n * 409600;

    f32x4 acc[4][4];
#pragma unroll
    for (int a = 0; a < 4; ++a)
#pragma unroll
        for (int b = 0; b < 4; ++b) acc[a][b] = (f32x4)0.f;

    int rbase = lane & 15;
    int koff = (lane >> 4) * 8;
    int base = c0 - 75;
    int aoff[4];
#pragma unroll
    for (int mb = 0; mb < 4; ++mb)
        aoff[mb] = (wm * 64 + mb * 16 + rbase) * 1024 + koff;

    for (int ic = 0; ic < 4; ++ic) {
        int i0 = ic * 32;
        __syncthreads();
        for (int L = tid; L < 1112; L += 256) {
            int w = L >> 2, g = (L & 3) * 8;
            int cs = base + w;
            ushort8 vh = (ushort8)0;
            if (cs >= 0 && cs < 3200)
                vh = *(const ushort8*)&x2h_n[(size_t)cs * 128 + i0 + g];
            *(ushort8*)&Bh[w][g] = vh;
        }
        __syncthreads();
        short8 afn[4];
#pragma unroll
        for (int mb = 0; mb < 4; ++mb)
            afn[mb] = *(const short8*)&wAhi[aoff[mb] + i0];
#pragma unroll
        for (int tap = 0; tap < 8; ++tap) {
            short8 af[4];
#pragma unroll
            for (int mb = 0; mb < 4; ++mb) af[mb] = afn[mb];
            if (tap < 7) {
#pragma unroll
                for (int mb = 0; mb < 4; ++mb)
                    afn[mb] = *(const short8*)&wAhi[aoff[mb] + (tap + 1) * 128 + i0];
            }
            int wofs = (tap < 7) ? 25 * tap : 75;
            short8 bf[4];
#pragma unroll
            for (int nb = 0; nb < 4; ++nb)
                bf[nb] = *(const short8*)&Bh[wn * 64 + nb * 16 + rbase + wofs][koff];
#pragma unroll
            for (int mb = 0; mb < 4; ++mb)
#pragma unroll
                for (int nb = 0; nb < 4; ++nb)
                    acc[mb][nb] = __builtin_amdgcn_mfma_f32_16x16x32_bf16(af[mb], bf[nb], acc[mb][nb], 0, 0, 0);
        }
    }
#pragma unroll
    for (int mb = 0; mb < 4; ++mb) {
#pragma unroll
        for (int nb = 0; nb < 4; ++nb) {
            int col = c0 + wn * 64 + nb * 16 + (lane & 15);
#pragma unroll
            for (int r = 0; r < 4; ++r) {
                int o = wm * 64 + mb * 16 + (lane >> 4) * 4 + r;
                float y = acc[mb][nb][r] + bcomb[o];
                out[((size_t)n * 128 + o) * 3200 + col] = lrelu(y);
            }
        }
    }
}

extern "C" void kernel_launch(void* const* d_in, const int* in_sizes, int n_in,
                              void* d_out, int out_size, void* d_ws, size_t ws_size,
                              hipStream_t stream)
{
    const float* x       = (const float*)d_in[0];
    const float* w_qkv   = (const float*)d_in[1];
    const float* b_qkv   = (const float*)d_in[2];
    const float* values  = (const float*)d_in[3];
    const float* att_bias= (const float*)d_in[4];
    const float* w_out   = (const float*)d_in[5];
    const float* b_out   = (const float*)d_in[6];
    const float* g_out   = (const float*)d_in[7];
    const float* be_out  = (const float*)d_in[8];
    const float* m_out   = (const float*)d_in[9];
    const float* v_out   = (const float*)d_in[10];
    const float* w_ff    = (const float*)d_in[11];
    const float* b_ff    = (const float*)d_in[12];
    const float* g_ff    = (const float*)d_in[13];
    const float* be_ff   = (const float*)d_in[14];
    const float* m_ff    = (const float*)d_in[15];
    const float* v_ff    = (const float*)d_in[16];
    const float* w_t     = (const float*)d_in[17];
    const float* b_t     = (const float*)d_in[18];
    const float* g_t     = (const float*)d_in[19];
    const float* be_t    = (const float*)d_in[20];
    const float* m_t     = (const float*)d_in[21];
    const float* v_t     = (const float*)d_in[22];
    const float* w_ress  = (const float*)d_in[23];
    const float* b_ress  = (const float*)d_in[24];
    const float* g_ress  = (const float*)d_in[25];
    const float* be_ress = (const float*)d_in[26];
    const float* m_ress  = (const float*)d_in[27];
    const float* v_ress  = (const float*)d_in[28];
    const float* w_rest  = (const float*)d_in[29];
    const float* b_rest  = (const float*)d_in[30];
    const float* g_rest  = (const float*)d_in[31];
    const float* be_rest = (const float*)d_in[32];
    const float* m_rest  = (const float*)d_in[33];
    const float* v_rest  = (const float*)d_in[34];

    float* ws = (float*)d_ws;
    float* out = (float*)d_out;

    unsigned short* xthi = (unsigned short*)(ws + OFF_XTHI);
    unsigned short* qk   = (unsigned short*)(ws + OFF_BIG);
    float*          part = ws + OFF_PART;
    unsigned short* tmhi = (unsigned short*)(ws + OFF_BIG);
    unsigned short* x2hi = (unsigned short*)(ws + OFF_BIG);
    unsigned short* x1hi = (unsigned short*)out;

    k0_prep<<<128, 256, 0, stream>>>(w_qkv,
        w_out, b_out, g_out, be_out, m_out, v_out,
        w_ff, b_ff, g_ff, be_ff, m_ff, v_ff,
        w_t, b_t, g_t, be_t, m_t, v_t,
        w_ress, b_ress, g_ress, be_ress, m_ress, v_ress,
        w_rest, b_rest, g_rest, be_rest, m_rest, v_rest,
        ws);
    k_xt<<<N_ * T_, 256, 0, stream>>>(x, xthi);
    k1_mfma<<<N_ * 25, 256, 0, stream>>>(
        (const unsigned short*)(ws + OFF_WQHI), xthi, b_qkv, qk);
    k2_att<<<N_ * H_ * 4, 256, 0, stream>>>(qk, part);
    k2b_smax<<<N_ * H_, 64, 0, stream>>>(part, values, att_bias, ws + OFF_ATT);
    k_tm<<<N_ * T_, 192, 0, stream>>>(x, ws + OFF_ATT, tmhi);
    k3_mfma<<<N_ * 25, 256, 0, stream>>>(
        (const unsigned short*)(ws + OFF_WA3HI), tmhi, xthi, ws + OFF_B3, x1hi);
    k4_mfma<<<N_ * 25, 256, 0, stream>>>(
        (const unsigned short*)(ws + OFF_WA4HI), x1hi, xthi, ws + OFF_B4, x2hi);
    k5_mfma<<<N_ * 25, 256, 0, stream>>>(
        (const unsigned short*)(ws + OFF_WA5HI), x2hi, ws + OFF_B5, out);
}